// Round 2
// baseline (5078.075 us; speedup 1.0000x reference)
//
#include <hip/hip_runtime.h>
#include <hip/hip_bf16.h>
#include <math.h>

#define B_    2
#define CIN   512
#define S_    1024
#define D_    768
#define NH    12
#define HD_   64
#define E_    8
#define FF_   2048
#define T_    2048              // B*S tokens
#define FBINS 513
#define NS2   1026              // 2*FBINS
#define WIN_  1024
#define HOP_  256
#define PAD_  384
#define OUTP  262144            // per-batch trimmed output length

static inline int cdiv(int a, int b) { return (a + b - 1) / b; }

__device__ inline float gelu_f(float x) {
    float x3 = x * x * x;
    return 0.5f * x * (1.0f + tanhf(0.7978845608028654f * (x + 0.044715f * x3)));
}

// ---------------- transpose z: [B,CIN,S] -> xT[t, c] (t = b*S + l) ----------------
__global__ void tz_k(const float* __restrict__ z, float* __restrict__ xT) {
    int id = blockIdx.x * 256 + threadIdx.x;            // t*CIN + c
    if (id >= T_ * CIN) return;
    int t = id >> 9, c = id & 511;
    int b = t >> 10, l = t & 1023;
    xT[id] = z[((size_t)b * CIN + c) * S_ + l];
}

// ---------------- generic tiled GEMM: C[M,N] (+=) A[M,K] * B[K,N] + bias ----------------
// EPI 0: C = v + bias ; EPI 1: C += v + bias
template <int EPI>
__global__ void gemm_k(const float* __restrict__ A, const float* __restrict__ B,
                       const float* __restrict__ bias, float* __restrict__ C,
                       int M, int N, int Kd) {
    __shared__ float As[16][65];
    __shared__ float Bs[16][65];
    int tid = threadIdx.x;
    int tx = tid & 15, ty = tid >> 4;
    int m0 = blockIdx.y * 64, n0 = blockIdx.x * 64;
    float acc[4][4] = {};
    int nk = (Kd + 15) >> 4;
    for (int kt = 0; kt < nk; ++kt) {
        int k0 = kt << 4;
        {
            int row = tid >> 2;
            int kk = (tid & 3) << 2;
            int gm = m0 + row, gk = k0 + kk;
#pragma unroll
            for (int i = 0; i < 4; ++i) {
                float v = 0.0f;
                if (gm < M && (gk + i) < Kd) v = A[(size_t)gm * Kd + gk + i];
                As[kk + i][row] = v;
            }
        }
        {
            int row = tid >> 4;
            int c0 = (tid & 15) << 2;
            int gk = k0 + row;
#pragma unroll
            for (int i = 0; i < 4; ++i) {
                float v = 0.0f;
                int gn = n0 + c0 + i;
                if (gk < Kd && gn < N) v = B[(size_t)gk * N + gn];
                Bs[row][c0 + i] = v;
            }
        }
        __syncthreads();
#pragma unroll
        for (int kk = 0; kk < 16; ++kk) {
            float a[4], b[4];
#pragma unroll
            for (int i = 0; i < 4; ++i) a[i] = As[kk][ty * 4 + i];
#pragma unroll
            for (int j = 0; j < 4; ++j) b[j] = Bs[kk][tx * 4 + j];
#pragma unroll
            for (int i = 0; i < 4; ++i)
#pragma unroll
                for (int j = 0; j < 4; ++j) acc[i][j] += a[i] * b[j];
        }
        __syncthreads();
    }
#pragma unroll
    for (int i = 0; i < 4; ++i) {
        int gm = m0 + ty * 4 + i;
        if (gm >= M) continue;
#pragma unroll
        for (int j = 0; j < 4; ++j) {
            int gn = n0 + tx * 4 + j;
            if (gn >= N) continue;
            float v = acc[i][j];
            if (bias) v += bias[gn];
            if (EPI == 1)
                C[(size_t)gm * N + gn] += v;
            else
                C[(size_t)gm * N + gn] = v;
        }
    }
}

// ---------------- grouped MoE GEMM (per-expert tiles with early exit) ----------------
template <bool GATHER, bool GELU>
__global__ void moe_gemm_k(const float* __restrict__ A, const float* __restrict__ Ball,
                           const float* __restrict__ biasAll, float* __restrict__ C,
                           const int* __restrict__ counts, const int* __restrict__ offsets,
                           const int* __restrict__ rowTok, int N, int Kd, size_t strideB,
                           int strideBias) {
    int e = blockIdx.z;
    int nrows = counts[e];
    int rt = blockIdx.y;
    if (rt * 64 >= nrows) return;
    int base = offsets[e];
    const float* Bm = Ball + (size_t)e * strideB;
    const float* bias = biasAll + (size_t)e * strideBias;
    __shared__ float As[16][65];
    __shared__ float Bs[16][65];
    __shared__ int rowIdx[64];
    int tid = threadIdx.x;
    if (tid < 64) {
        int rl = rt * 64 + tid;
        int src = -1;
        if (rl < nrows) src = GATHER ? rowTok[base + rl] : (base + rl);
        rowIdx[tid] = src;
    }
    __syncthreads();
    int tx = tid & 15, ty = tid >> 4;
    int n0 = blockIdx.x * 64;
    float acc[4][4] = {};
    int nk = (Kd + 15) >> 4;
    for (int kt = 0; kt < nk; ++kt) {
        int k0 = kt << 4;
        {
            int row = tid >> 2;
            int kk = (tid & 3) << 2;
            int src = rowIdx[row];
            int gk = k0 + kk;
#pragma unroll
            for (int i = 0; i < 4; ++i) {
                float v = 0.0f;
                if (src >= 0 && (gk + i) < Kd) v = A[(size_t)src * Kd + gk + i];
                As[kk + i][row] = v;
            }
        }
        {
            int row = tid >> 4;
            int c0 = (tid & 15) << 2;
            int gk = k0 + row;
#pragma unroll
            for (int i = 0; i < 4; ++i) {
                float v = 0.0f;
                int gn = n0 + c0 + i;
                if (gk < Kd && gn < N) v = Bm[(size_t)gk * N + gn];
                Bs[row][c0 + i] = v;
            }
        }
        __syncthreads();
#pragma unroll
        for (int kk = 0; kk < 16; ++kk) {
            float a[4], b[4];
#pragma unroll
            for (int i = 0; i < 4; ++i) a[i] = As[kk][ty * 4 + i];
#pragma unroll
            for (int j = 0; j < 4; ++j) b[j] = Bs[kk][tx * 4 + j];
#pragma unroll
            for (int i = 0; i < 4; ++i)
#pragma unroll
                for (int j = 0; j < 4; ++j) acc[i][j] += a[i] * b[j];
        }
        __syncthreads();
    }
#pragma unroll
    for (int i = 0; i < 4; ++i) {
        int rl = rt * 64 + ty * 4 + i;
        if (rl >= nrows) continue;
        int gr = base + rl;
#pragma unroll
        for (int j = 0; j < 4; ++j) {
            int gn = n0 + tx * 4 + j;
            if (gn >= N) continue;
            float v = acc[i][j] + bias[gn];
            if (GELU) v = gelu_f(v);
            C[(size_t)gr * N + gn] = v;
        }
    }
}

// ---------------- LayerNorm per token ----------------
__global__ void ln_k(const float* __restrict__ x, const float* __restrict__ g,
                     const float* __restrict__ b, float* __restrict__ h) {
    int t = blockIdx.x;
    int tid = threadIdx.x;
    __shared__ float row[D_];
    __shared__ float red[256];
    const float* xr = x + (size_t)t * D_;
    float s = 0.0f;
    for (int i = tid; i < D_; i += 256) {
        float v = xr[i];
        row[i] = v;
        s += v;
    }
    red[tid] = s;
    __syncthreads();
    for (int st = 128; st > 0; st >>= 1) {
        if (tid < st) red[tid] += red[tid + st];
        __syncthreads();
    }
    float mean = red[0] / (float)D_;
    __syncthreads();
    float s2 = 0.0f;
    for (int i = tid; i < D_; i += 256) {
        float d = row[i] - mean;
        s2 += d * d;
    }
    red[tid] = s2;
    __syncthreads();
    for (int st = 128; st > 0; st >>= 1) {
        if (tid < st) red[tid] += red[tid + st];
        __syncthreads();
    }
    float rstd = rsqrtf(red[0] / (float)D_ + 1e-5f);
    for (int i = tid; i < D_; i += 256) {
        h[(size_t)t * D_ + i] = (row[i] - mean) * rstd * g[i] + b[i];
    }
}

// ---------------- RoPE (full dim, interleaved pairs) in place ----------------
__global__ void rope_k(float* __restrict__ x) {
    int id = blockIdx.x * 256 + threadIdx.x;  // t*384 + j
    if (id >= T_ * 384) return;
    int t = id / 384, j = id % 384;
    int pos = t & 1023;
    float inv = expf(-(float)j * (9.210340371976184f / 384.0f));  // 10000^(-j/384)
    float ang = (float)pos * inv;
    float sn, cs;
    sincosf(ang, &sn, &cs);
    float* p = x + (size_t)t * D_ + 2 * j;
    float x1 = p[0], x2 = p[1];
    p[0] = x1 * cs - x2 * sn;
    p[1] = x1 * sn + x2 * cs;
}

// ---------------- causal attention, one block per (q, head, batch) ----------------
__global__ void attn_k(const float* __restrict__ q, const float* __restrict__ k,
                       const float* __restrict__ v, float* __restrict__ ctx) {
    int qi = blockIdx.x;
    int h = blockIdx.y;
    int b = blockIdx.z;
    int tid = threadIdx.x;
    __shared__ float qv[HD_];
    __shared__ float sc[S_];
    __shared__ float red[256];
    __shared__ float part[4][HD_];
    size_t rowQ = ((size_t)(b * S_ + qi)) * D_ + h * HD_;
    if (tid < HD_) qv[tid] = q[rowQ + tid];
    __syncthreads();
    float lmax = -1e30f;
    for (int j = tid; j <= qi; j += 256) {
        const float* kr = k + ((size_t)(b * S_ + j)) * D_ + h * HD_;
        float s = 0.0f;
#pragma unroll
        for (int d4 = 0; d4 < HD_; d4 += 4) {
            float4 kk4 = *(const float4*)(kr + d4);
            s += qv[d4] * kk4.x + qv[d4 + 1] * kk4.y + qv[d4 + 2] * kk4.z + qv[d4 + 3] * kk4.w;
        }
        s *= 0.125f;
        sc[j] = s;
        lmax = fmaxf(lmax, s);
    }
    red[tid] = lmax;
    __syncthreads();
    for (int st = 128; st > 0; st >>= 1) {
        if (tid < st) red[tid] = fmaxf(red[tid], red[tid + st]);
        __syncthreads();
    }
    float m = red[0];
    __syncthreads();
    float lsum = 0.0f;
    for (int j = tid; j <= qi; j += 256) {
        float e = expf(sc[j] - m);
        sc[j] = e;
        lsum += e;
    }
    red[tid] = lsum;
    __syncthreads();
    for (int st = 128; st > 0; st >>= 1) {
        if (tid < st) red[tid] += red[tid + st];
        __syncthreads();
    }
    float inv = 1.0f / red[0];
    __syncthreads();
    int d = tid & 63, seg = tid >> 6;
    float o = 0.0f;
    for (int j = seg; j <= qi; j += 4) {
        o += sc[j] * v[((size_t)(b * S_ + j)) * D_ + h * HD_ + d];
    }
    part[seg][d] = o;
    __syncthreads();
    if (tid < HD_) {
        float r = (part[0][tid] + part[1][tid] + part[2][tid] + part[3][tid]) * inv;
        ctx[rowQ + tid] = r;
    }
}

// ---------------- gating logits: h @ gate_w -> [T,8] ----------------
__global__ void gate_k(const float* __restrict__ h, const float* __restrict__ gw,
                       float* __restrict__ logits) {
    int t = blockIdx.x;
    int tid = threadIdx.x;
    __shared__ float row[D_];
    __shared__ float red[256];
    const float* hr = h + (size_t)t * D_;
    for (int i = tid; i < D_; i += 256) row[i] = hr[i];
    __syncthreads();
    int e = tid >> 5, lane = tid & 31;
    float s = 0.0f;
    for (int d = lane; d < D_; d += 32) s += row[d] * gw[d * E_ + e];
    red[tid] = s;
    __syncthreads();
    for (int st = 16; st > 0; st >>= 1) {
        if (lane < st) red[tid] += red[tid + st];
        __syncthreads();
    }
    if (lane == 0) logits[t * E_ + e] = red[tid];
}

__global__ void zero_meta_k(int* __restrict__ counts) {
    int i = threadIdx.x;
    if (i < E_) counts[i] = 0;
}

__global__ void top2_k(const float* __restrict__ logits, int* __restrict__ counts,
                       int* __restrict__ tokE, float* __restrict__ tokW) {
    int t = blockIdx.x * 256 + threadIdx.x;
    if (t >= T_) return;
    const float* l = logits + t * E_;
    int i0 = 0;
    float v0 = l[0];
    for (int e = 1; e < E_; ++e) {
        float v = l[e];
        if (v > v0) { v0 = v; i0 = e; }
    }
    int i1 = -1;
    float v1 = -1e30f;
    for (int e = 0; e < E_; ++e) {
        if (e == i0) continue;
        float v = l[e];
        if (v > v1) { v1 = v; i1 = e; }
    }
    float e2 = expf(v1 - v0);
    float w0 = 1.0f / (1.0f + e2);
    float w1 = e2 * w0;
    tokE[2 * t] = i0;
    tokE[2 * t + 1] = i1;
    tokW[2 * t] = w0;
    tokW[2 * t + 1] = w1;
    atomicAdd(&counts[i0], 1);
    atomicAdd(&counts[i1], 1);
}

__global__ void offsets_k(const int* __restrict__ counts, int* __restrict__ offsets,
                          int* __restrict__ cursor) {
    if (threadIdx.x == 0 && blockIdx.x == 0) {
        int a = 0;
        for (int e = 0; e < E_; ++e) {
            offsets[e] = a;
            cursor[e] = a;
            a += counts[e];
        }
    }
}

__global__ void assign_k(const int* __restrict__ tokE, int* __restrict__ cursor,
                         int* __restrict__ rowTok, int* __restrict__ tokRow) {
    int t = blockIdx.x * 256 + threadIdx.x;
    if (t >= T_) return;
    for (int s = 0; s < 2; ++s) {
        int e = tokE[2 * t + s];
        int r = atomicAdd(&cursor[e], 1);
        rowTok[r] = t;
        tokRow[2 * t + s] = r;
    }
}

__global__ void combine_k(const float* __restrict__ y2, const int* __restrict__ tokRow,
                          const float* __restrict__ tokW, float* __restrict__ x) {
    int id = blockIdx.x * 256 + threadIdx.x;  // t*D + d
    if (id >= T_ * D_) return;
    int t = id / D_, d = id % D_;
    x[id] += tokW[2 * t] * y2[(size_t)tokRow[2 * t] * D_ + d] +
             tokW[2 * t + 1] * y2[(size_t)tokRow[2 * t + 1] * D_ + d];
}

// ---------------- ISTFT basis: [1026][1024] (irfft coeffs * hann window, 1/N folded) ----------------
__global__ void basis_k(float* __restrict__ basis) {
    int id = blockIdx.x * 256 + threadIdx.x;  // j*1024 + n
    if (id >= NS2 * WIN_) return;
    int j = id >> 10, n = id & 1023;
    float wn = 0.5f - 0.5f * cosf(6.283185307179586f * (float)n / 1024.0f);
    int kf = (j < FBINS) ? j : (j - FBINS);
    float scale = (kf == 0 || kf == 512) ? (1.0f / 1024.0f) : (2.0f / 1024.0f);
    int m = (kf * n) & 1023;  // exact integer phase reduction
    float th = 6.283185307179586f * (float)m / 1024.0f;
    float val;
    if (j < FBINS)
        val = scale * cosf(th);
    else
        val = (kf == 0 || kf == 512) ? 0.0f : (-scale * sinf(th));
    basis[id] = val * wn;
}

// ---------------- overlap-add + env normalize + trim + store ----------------
__global__ void ola_k(const float* __restrict__ frames, float* __restrict__ out, int total) {
    int id = blockIdx.x * 256 + threadIdx.x;  // b*OUTP + pout
    if (id >= total) return;
    int b = id / OUTP, pout = id % OUTP;
    int p = pout + PAD_;
    int t1 = p >> 8;
    if (t1 > S_ - 1) t1 = S_ - 1;
    int t0 = p - (WIN_ - 1) + (HOP_ - 1);
    t0 = (t0 > 0) ? (t0 >> 8) : 0;
    float acc = 0.0f, env = 0.0f;
    for (int t = t0; t <= t1; ++t) {
        int n = p - (t << 8);
        float wn = 0.5f - 0.5f * cosf(6.283185307179586f * (float)n / 1024.0f);
        acc += frames[(((size_t)(b * S_ + t)) << 10) + n];  // frames already windowed
        env += wn * wn;
    }
    out[id] = acc / env;
}

// ======================= launcher =======================
extern "C" void kernel_launch(void* const* d_in, const int* in_sizes, int n_in, void* d_out,
                              int out_size, void* d_ws, size_t ws_size, hipStream_t stream) {
    const float* z    = (const float*)d_in[0];
    const float* in_w = (const float*)d_in[1];
    const float* in_b = (const float*)d_in[2];
    const float* ln1g = (const float*)d_in[3];
    const float* ln1b = (const float*)d_in[4];
    const float* wq   = (const float*)d_in[5];
    const float* bq   = (const float*)d_in[6];
    const float* wk   = (const float*)d_in[7];
    const float* bk   = (const float*)d_in[8];
    const float* wv   = (const float*)d_in[9];
    const float* bv   = (const float*)d_in[10];
    const float* wo   = (const float*)d_in[11];
    const float* bo   = (const float*)d_in[12];
    const float* ln2g = (const float*)d_in[13];
    const float* ln2b = (const float*)d_in[14];
    const float* gw   = (const float*)d_in[15];
    const float* ew1  = (const float*)d_in[16];
    const float* eb1  = (const float*)d_in[17];
    const float* ew2  = (const float*)d_in[18];
    const float* eb2  = (const float*)d_in[19];
    const float* outw = (const float*)d_in[20];
    const float* outb = (const float*)d_in[21];

    float* ws = (float*)d_ws;
    int* wsi = (int*)d_ws;
    const size_t TD = (size_t)T_ * D_;
    const size_t o_x = 0;
    const size_t o_h = TD;
    const size_t o_q = 2 * TD;
    const size_t o_k = 3 * TD;
    const size_t o_v = 4 * TD;
    const size_t o_ctx = 5 * TD;
    const size_t o_logits = 6 * TD;               // T*8 floats
    const size_t o_counts = o_logits + T_ * E_;   // ints
    const size_t o_cursor = o_counts + 8;
    const size_t o_offs = o_cursor + 8;
    const size_t o_tokE = o_offs + 16;            // 2T ints
    const size_t o_rowTok = o_tokE + 2 * T_;      // 2T ints
    const size_t o_tokRow = o_rowTok + 2 * T_;    // 2T ints
    const size_t o_tokW = o_tokRow + 2 * T_;      // 2T floats
    const size_t o_big = o_tokW + 2 * T_;
    const size_t o_h1 = o_big;
    const size_t o_y2 = o_h1 + (size_t)2 * T_ * FF_;
    const size_t o_xT = o_big;
    const size_t o_s = o_big;
    const size_t o_basis = o_s + (size_t)T_ * NS2;
    const size_t o_frames = o_basis + (size_t)NS2 * WIN_;
    const size_t total_f = o_y2 + (size_t)2 * T_ * D_;
    if (ws_size < total_f * sizeof(float)) return;  // workspace too small -> fail loudly

    dim3 blk(256);

    // ---- in projection ----
    tz_k<<<cdiv(T_ * CIN, 256), blk, 0, stream>>>(z, ws + o_xT);
    gemm_k<0><<<dim3(cdiv(D_, 64), cdiv(T_, 64)), blk, 0, stream>>>(ws + o_xT, in_w, in_b,
                                                                    ws + o_x, T_, D_, CIN);

    for (int i = 0; i < 2; ++i) {
        const size_t wOff = (size_t)i * D_ * D_;
        const size_t bOff = (size_t)i * D_;
        // LN1
        ln_k<<<T_, blk, 0, stream>>>(ws + o_x, ln1g + bOff, ln1b + bOff, ws + o_h);
        // QKV
        gemm_k<0><<<dim3(12, 32), blk, 0, stream>>>(ws + o_h, wq + wOff, bq + bOff, ws + o_q,
                                                    T_, D_, D_);
        gemm_k<0><<<dim3(12, 32), blk, 0, stream>>>(ws + o_h, wk + wOff, bk + bOff, ws + o_k,
                                                    T_, D_, D_);
        gemm_k<0><<<dim3(12, 32), blk, 0, stream>>>(ws + o_h, wv + wOff, bv + bOff, ws + o_v,
                                                    T_, D_, D_);
        if (i == 0) {
            rope_k<<<cdiv(T_ * 384, 256), blk, 0, stream>>>(ws + o_q);
            rope_k<<<cdiv(T_ * 384, 256), blk, 0, stream>>>(ws + o_k);
        }
        // attention
        attn_k<<<dim3(S_, NH, B_), blk, 0, stream>>>(ws + o_q, ws + o_k, ws + o_v, ws + o_ctx);
        // O-proj + residual
        gemm_k<1><<<dim3(12, 32), blk, 0, stream>>>(ws + o_ctx, wo + wOff, bo + bOff, ws + o_x,
                                                    T_, D_, D_);
        // LN2
        ln_k<<<T_, blk, 0, stream>>>(ws + o_x, ln2g + bOff, ln2b + bOff, ws + o_h);
        // gating
        gate_k<<<T_, blk, 0, stream>>>(ws + o_h, gw + (size_t)i * D_ * E_, ws + o_logits);
        zero_meta_k<<<1, 64, 0, stream>>>(wsi + o_counts);
        top2_k<<<cdiv(T_, 256), blk, 0, stream>>>(ws + o_logits, wsi + o_counts, wsi + o_tokE,
                                                  ws + o_tokW);
        offsets_k<<<1, 64, 0, stream>>>(wsi + o_counts, wsi + o_offs, wsi + o_cursor);
        assign_k<<<cdiv(T_, 256), blk, 0, stream>>>(wsi + o_tokE, wsi + o_cursor, wsi + o_rowTok,
                                                    wsi + o_tokRow);
        // expert FFN (grouped)
        moe_gemm_k<true, true><<<dim3(FF_ / 64, 64, E_), blk, 0, stream>>>(
            ws + o_h, ew1 + (size_t)i * E_ * D_ * FF_, eb1 + (size_t)i * E_ * FF_, ws + o_h1,
            wsi + o_counts, wsi + o_offs, wsi + o_rowTok, FF_, D_, (size_t)D_ * FF_, FF_);
        moe_gemm_k<false, false><<<dim3(D_ / 64, 64, E_), blk, 0, stream>>>(
            ws + o_h1, ew2 + (size_t)i * E_ * FF_ * D_, eb2 + (size_t)i * E_ * D_, ws + o_y2,
            wsi + o_counts, wsi + o_offs, wsi + o_rowTok, D_, FF_, (size_t)FF_ * D_, D_);
        combine_k<<<cdiv(T_ * D_, 256), blk, 0, stream>>>(ws + o_y2, wsi + o_tokRow, ws + o_tokW,
                                                          ws + o_x);
    }

    // ---- output projection ----
    gemm_k<0><<<dim3(cdiv(NS2, 64), 32), blk, 0, stream>>>(ws + o_x, outw, outb, ws + o_s, T_,
                                                           NS2, D_);
    // ---- ISTFT ----
    basis_k<<<cdiv(NS2 * WIN_, 256), blk, 0, stream>>>(ws + o_basis);
    gemm_k<0><<<dim3(WIN_ / 64, 32), blk, 0, stream>>>(ws + o_s, ws + o_basis, (const float*)nullptr,
                                                       ws + o_frames, T_, WIN_, NS2);
    ola_k<<<cdiv(out_size, 256), blk, 0, stream>>>(ws + o_frames, (float*)d_out, out_size);
}

// Round 5
// 3673.881 us; speedup vs baseline: 1.3822x; 1.3822x over previous
//
#include <hip/hip_runtime.h>
#include <hip/hip_bf16.h>
#include <math.h>

#define B_    2
#define CIN   512
#define S_    1024
#define D_    768
#define NH    12
#define HD_   64
#define E_    8
#define FF_   2048
#define T_    2048
#define FBINS 513
#define NS2   1026
#define KPAD  1056              // NS2 padded to mult of 32
#define NPADO 1152              // NS2 padded to mult of 128
#define WIN_  1024
#define HOP_  256
#define PAD_  384
#define OUTP  262144
#define AGR   4224              // 2T + 128 pad rows

static inline int cdiv(int a, int b) { return (a + b - 1) / b; }

typedef _Float16 half8 __attribute__((ext_vector_type(8)));
typedef __attribute__((ext_vector_type(4))) float floatx4;

#define MFMA16(a, b, c) __builtin_amdgcn_mfma_f32_16x16x32_f16(a, b, c, 0, 0, 0)
#define LO_SCALE 2048.0f
#define LO_INV   (1.0f / 2048.0f)

// split fp32 -> (hi fp16, lo fp16 scaled by 2048); planes are short-typed
__device__ inline void split_store(float v, short* p, size_t planeOff) {
    _Float16 h = (_Float16)v;
    _Float16 l = (_Float16)((v - (float)h) * LO_SCALE);
    *(_Float16*)p = h;
    *(_Float16*)(p + planeOff) = l;
}

__device__ inline float gelu_f(float x) {
    float x3 = x * x * x;
    return 0.5f * x * (1.0f + tanhf(0.7978845608028654f * (x + 0.044715f * x3)));
}

__device__ inline void gl_lds16(const short* g, short* l) {
    __builtin_amdgcn_global_load_lds((const __attribute__((address_space(1))) void*)g,
                                     (__attribute__((address_space(3))) void*)l, 16, 0, 0);
}

// ===== split-fp16 MFMA GEMM core (128x128 tile, BK=32, 3 MFMAs per frag pair) =====
// MODE 0: f32 store; 1: f32 +=; 2: split-pair store; 3: gelu -> split-pair store
template <int MODE>
__global__ __launch_bounds__(256) void mm2_k(
    const short* __restrict__ Ah, const short* __restrict__ Al,
    const short* __restrict__ Bh, const short* __restrict__ Bl,
    const float* __restrict__ bias, float* __restrict__ Cf,
    short* __restrict__ Cp, size_t CpPl,
    int Nstore, int K, int SA, int SB, int SC) {
    __shared__ short AsH[4096], AsL[4096], BsH[4096], BsL[4096];
    int tid = threadIdx.x;
    int wave = tid >> 6, lane = tid & 63;
    int m0 = blockIdx.y * 128, n0 = blockIdx.x * 128;
    int wm = (wave & 1) * 64, wn = (wave >> 1) * 64;
    floatx4 a1[4][4], a2[4][4];
#pragma unroll
    for (int i = 0; i < 4; ++i)
#pragma unroll
        for (int j = 0; j < 4; ++j) {
            a1[i][j] = (floatx4){0.f, 0.f, 0.f, 0.f};
            a2[i][j] = (floatx4){0.f, 0.f, 0.f, 0.f};
        }
    int lm = lane & 15, lk = (lane >> 4) * 8;
    int fl0 = wave * 64 + lane, fl1 = fl0 + 256;
    int r0 = fl0 >> 2, c0 = (fl0 & 3) * 8;
    int r1 = fl1 >> 2, c1 = (fl1 & 3) * 8;
    int kIters = K >> 5;
    for (int kt = 0; kt < kIters; ++kt) {
        int k0 = kt << 5;
        size_t a0 = (size_t)(m0 + r0) * SA + k0 + c0;
        size_t a1o = (size_t)(m0 + r1) * SA + k0 + c1;
        size_t b0 = (size_t)(n0 + r0) * SB + k0 + c0;
        size_t b1 = (size_t)(n0 + r1) * SB + k0 + c1;
        gl_lds16(Ah + a0, AsH + wave * 512);
        gl_lds16(Ah + a1o, AsH + (wave + 4) * 512);
        gl_lds16(Al + a0, AsL + wave * 512);
        gl_lds16(Al + a1o, AsL + (wave + 4) * 512);
        gl_lds16(Bh + b0, BsH + wave * 512);
        gl_lds16(Bh + b1, BsH + (wave + 4) * 512);
        gl_lds16(Bl + b0, BsL + wave * 512);
        gl_lds16(Bl + b1, BsL + (wave + 4) * 512);
        __syncthreads();
        half8 ah[4], al[4], bh[4], bl[4];
#pragma unroll
        for (int i = 0; i < 4; ++i) {
            int off = (wm + i * 16 + lm) * 32 + lk;
            ah[i] = *(const half8*)(AsH + off);
            al[i] = *(const half8*)(AsL + off);
        }
#pragma unroll
        for (int j = 0; j < 4; ++j) {
            int off = (wn + j * 16 + lm) * 32 + lk;
            bh[j] = *(const half8*)(BsH + off);
            bl[j] = *(const half8*)(BsL + off);
        }
#pragma unroll
        for (int i = 0; i < 4; ++i)
#pragma unroll
            for (int j = 0; j < 4; ++j) {
                a1[i][j] = MFMA16(ah[i], bh[j], a1[i][j]);
                a2[i][j] = MFMA16(ah[i], bl[j], a2[i][j]);
                a2[i][j] = MFMA16(al[i], bh[j], a2[i][j]);
            }
        __syncthreads();
    }
    int row4 = (lane >> 4) * 4;
#pragma unroll
    for (int i = 0; i < 4; ++i) {
        int row = m0 + wm + i * 16 + row4;
#pragma unroll
        for (int j = 0; j < 4; ++j) {
            int col = n0 + wn + j * 16 + lm;
            if (col < Nstore) {
                float bv = bias ? bias[col] : 0.0f;
#pragma unroll
                for (int r = 0; r < 4; ++r) {
                    float v = a1[i][j][r] + a2[i][j][r] * LO_INV + bv;
                    size_t idx = (size_t)(row + r) * SC + col;
                    if (MODE == 0) Cf[idx] = v;
                    else if (MODE == 1) Cf[idx] += v;
                    else if (MODE == 2) split_store(v, Cp + idx, CpPl);
                    else split_store(gelu_f(v), Cp + idx, CpPl);
                }
            }
        }
    }
}

// ===== grouped MoE variant over expert row-segments (2 experts per launch) =====
template <int MODE>
__global__ __launch_bounds__(256) void mm2_moe_k(
    const short* __restrict__ Agh, const short* __restrict__ Agl,
    const short* __restrict__ BT, size_t eStride, size_t bPl,
    const float* __restrict__ biasAll, int biasStride,
    float* __restrict__ Cf, short* __restrict__ Cp, size_t CpPl,
    const int* __restrict__ counts, const int* __restrict__ offsets,
    int N, int K, int SA, int SB, int SC) {
    int el = blockIdx.z;
    int nrows = counts[el];
    int m0 = blockIdx.y * 128;
    if (m0 >= nrows) return;
    int base = offsets[el];
    const short* Ah = Agh + (size_t)base * SA;
    const short* Al = Agl + (size_t)base * SA;
    const short* Bh = BT + (size_t)el * eStride;
    const short* Bl = Bh + bPl;
    const float* bias = biasAll + (size_t)el * biasStride;
    __shared__ short AsH[4096], AsL[4096], BsH[4096], BsL[4096];
    int tid = threadIdx.x;
    int wave = tid >> 6, lane = tid & 63;
    int n0 = blockIdx.x * 128;
    int wm = (wave & 1) * 64, wn = (wave >> 1) * 64;
    floatx4 a1[4][4], a2[4][4];
#pragma unroll
    for (int i = 0; i < 4; ++i)
#pragma unroll
        for (int j = 0; j < 4; ++j) {
            a1[i][j] = (floatx4){0.f, 0.f, 0.f, 0.f};
            a2[i][j] = (floatx4){0.f, 0.f, 0.f, 0.f};
        }
    int lm = lane & 15, lk = (lane >> 4) * 8;
    int fl0 = wave * 64 + lane, fl1 = fl0 + 256;
    int r0 = fl0 >> 2, c0 = (fl0 & 3) * 8;
    int r1 = fl1 >> 2, c1 = (fl1 & 3) * 8;
    int kIters = K >> 5;
    for (int kt = 0; kt < kIters; ++kt) {
        int k0 = kt << 5;
        size_t a0 = (size_t)(m0 + r0) * SA + k0 + c0;
        size_t a1o = (size_t)(m0 + r1) * SA + k0 + c1;
        size_t b0 = (size_t)(n0 + r0) * SB + k0 + c0;
        size_t b1 = (size_t)(n0 + r1) * SB + k0 + c1;
        gl_lds16(Ah + a0, AsH + wave * 512);
        gl_lds16(Ah + a1o, AsH + (wave + 4) * 512);
        gl_lds16(Al + a0, AsL + wave * 512);
        gl_lds16(Al + a1o, AsL + (wave + 4) * 512);
        gl_lds16(Bh + b0, BsH + wave * 512);
        gl_lds16(Bh + b1, BsH + (wave + 4) * 512);
        gl_lds16(Bl + b0, BsL + wave * 512);
        gl_lds16(Bl + b1, BsL + (wave + 4) * 512);
        __syncthreads();
        half8 ah[4], al[4], bh[4], bl[4];
#pragma unroll
        for (int i = 0; i < 4; ++i) {
            int off = (wm + i * 16 + lm) * 32 + lk;
            ah[i] = *(const half8*)(AsH + off);
            al[i] = *(const half8*)(AsL + off);
        }
#pragma unroll
        for (int j = 0; j < 4; ++j) {
            int off = (wn + j * 16 + lm) * 32 + lk;
            bh[j] = *(const half8*)(BsH + off);
            bl[j] = *(const half8*)(BsL + off);
        }
#pragma unroll
        for (int i = 0; i < 4; ++i)
#pragma unroll
            for (int j = 0; j < 4; ++j) {
                a1[i][j] = MFMA16(ah[i], bh[j], a1[i][j]);
                a2[i][j] = MFMA16(ah[i], bl[j], a2[i][j]);
                a2[i][j] = MFMA16(al[i], bh[j], a2[i][j]);
            }
        __syncthreads();
    }
    int row4 = (lane >> 4) * 4;
#pragma unroll
    for (int i = 0; i < 4; ++i) {
        int rl = m0 + wm + i * 16 + row4;
#pragma unroll
        for (int j = 0; j < 4; ++j) {
            int col = n0 + wn + j * 16 + lm;
            if (col < N) {
                float bv = bias[col];
#pragma unroll
                for (int r = 0; r < 4; ++r) {
                    if (rl + r < nrows) {
                        float v = a1[i][j][r] + a2[i][j][r] * LO_INV + bv;
                        size_t idx = (size_t)(base + rl + r) * SC + col;
                        if (MODE == 0) Cf[idx] = v;
                        else split_store(gelu_f(v), Cp + idx, CpPl);
                    }
                }
            }
        }
    }
}

// ===== transpose fp32 [Z][R][C] -> split-pair [Z][Cout][R] (zero rows c>=C) =====
__global__ __launch_bounds__(256) void transp2_k(const float* __restrict__ src,
                                                 short* __restrict__ dst, int R, int C, int Cout,
                                                 size_t srcZ, size_t dstZ, size_t planeOff) {
    __shared__ float tile[32][33];
    int z = blockIdx.z;
    src += (size_t)z * srcZ;
    dst += (size_t)z * dstZ;
    int c0 = blockIdx.x * 32, r0 = blockIdx.y * 32;
    int tx = threadIdx.x & 31, ty = threadIdx.x >> 5;
    for (int i = ty; i < 32; i += 8) {
        int r = r0 + i, c = c0 + tx;
        tile[i][tx] = (r < R && c < C) ? src[(size_t)r * C + c] : 0.0f;
    }
    __syncthreads();
    for (int i = ty; i < 32; i += 8) {
        int cc = c0 + i, rr = r0 + tx;
        if (cc < Cout && rr < R) split_store(tile[tx][i], dst + (size_t)cc * R + rr, planeOff);
    }
}

// ===== transpose z: [B,CIN,S] -> zT pair [t][c] =====
__global__ __launch_bounds__(256) void tz2_k(const float* __restrict__ z, short* __restrict__ xT,
                                             size_t planeOff) {
    int id = blockIdx.x * 256 + threadIdx.x;
    if (id >= T_ * CIN) return;
    int t = id >> 9, c = id & 511;
    int b = t >> 10, l = t & 1023;
    split_store(z[((size_t)b * CIN + c) * S_ + l], xT + id, planeOff);
}

// ===== LayerNorm per token -> split pair =====
__global__ __launch_bounds__(256) void ln_k(const float* __restrict__ x,
                                            const float* __restrict__ g,
                                            const float* __restrict__ b, short* __restrict__ h,
                                            size_t planeOff) {
    int t = blockIdx.x;
    int tid = threadIdx.x;
    __shared__ float row[D_];
    __shared__ float red[256];
    const float* xr = x + (size_t)t * D_;
    float s = 0.0f;
    for (int i = tid; i < D_; i += 256) {
        float v = xr[i];
        row[i] = v;
        s += v;
    }
    red[tid] = s;
    __syncthreads();
    for (int st = 128; st > 0; st >>= 1) {
        if (tid < st) red[tid] += red[tid + st];
        __syncthreads();
    }
    float mean = red[0] / (float)D_;
    __syncthreads();
    float s2 = 0.0f;
    for (int i = tid; i < D_; i += 256) {
        float d = row[i] - mean;
        s2 += d * d;
    }
    red[tid] = s2;
    __syncthreads();
    for (int st = 128; st > 0; st >>= 1) {
        if (tid < st) red[tid] += red[tid + st];
        __syncthreads();
    }
    float rstd = rsqrtf(red[0] / (float)D_ + 1e-5f);
    for (int i = tid; i < D_; i += 256)
        split_store((row[i] - mean) * rstd * g[i] + b[i], h + (size_t)t * D_ + i, planeOff);
}

// ===== fused fp32 LN + gating logits =====
__global__ __launch_bounds__(256) void lngate_k(const float* __restrict__ x,
                                                const float* __restrict__ g,
                                                const float* __restrict__ b,
                                                const float* __restrict__ gw,
                                                float* __restrict__ logits) {
    int t = blockIdx.x;
    int tid = threadIdx.x;
    __shared__ float row[D_];
    __shared__ float red[256];
    const float* xr = x + (size_t)t * D_;
    float s = 0.0f;
    for (int i = tid; i < D_; i += 256) {
        float v = xr[i];
        row[i] = v;
        s += v;
    }
    red[tid] = s;
    __syncthreads();
    for (int st = 128; st > 0; st >>= 1) {
        if (tid < st) red[tid] += red[tid + st];
        __syncthreads();
    }
    float mean = red[0] / (float)D_;
    __syncthreads();
    float s2 = 0.0f;
    for (int i = tid; i < D_; i += 256) {
        float d = row[i] - mean;
        s2 += d * d;
    }
    red[tid] = s2;
    __syncthreads();
    for (int st = 128; st > 0; st >>= 1) {
        if (tid < st) red[tid] += red[tid + st];
        __syncthreads();
    }
    float rstd = rsqrtf(red[0] / (float)D_ + 1e-5f);
    __syncthreads();
    int e = tid >> 5, lane = tid & 31;
    float acc = 0.0f;
    for (int d = lane; d < D_; d += 32)
        acc += ((row[d] - mean) * rstd * g[d] + b[d]) * gw[d * E_ + e];
    red[tid] = acc;
    __syncthreads();
    for (int st = 16; st > 0; st >>= 1) {
        if (lane < st) red[tid] += red[tid + st];
        __syncthreads();
    }
    if (lane == 0) logits[t * E_ + e] = red[tid];
}

// ===== RoPE in place (fp32 q/k) =====
__global__ __launch_bounds__(256) void rope_k(float* __restrict__ x) {
    int id = blockIdx.x * 256 + threadIdx.x;
    if (id >= T_ * 384) return;
    int t = id / 384, j = id % 384;
    int pos = t & 1023;
    float inv = expf(-(float)j * (9.210340371976184f / 384.0f));
    float ang = (float)pos * inv;
    float sn, cs;
    sincosf(ang, &sn, &cs);
    float* p = x + (size_t)t * D_ + 2 * j;
    float x1 = p[0], x2 = p[1];
    p[0] = x1 * cs - x2 * sn;
    p[1] = x1 * sn + x2 * cs;
}

// ===== causal attention (fp32, per-query block), split-pair ctx out =====
__global__ __launch_bounds__(256) void attn_k(const float* __restrict__ q,
                                              const float* __restrict__ k,
                                              const float* __restrict__ v,
                                              short* __restrict__ ctx, size_t ctxPl) {
    int qi = blockIdx.x;
    int h = blockIdx.y;
    int b = blockIdx.z;
    int tid = threadIdx.x;
    __shared__ float qv[HD_];
    __shared__ float sc[S_];
    __shared__ float red[256];
    __shared__ float part[4][HD_];
    size_t rowQ = ((size_t)(b * S_ + qi)) * D_ + h * HD_;
    if (tid < HD_) qv[tid] = q[rowQ + tid];
    __syncthreads();
    float lmax = -1e30f;
    for (int j = tid; j <= qi; j += 256) {
        const float* kr = k + ((size_t)(b * S_ + j)) * D_ + h * HD_;
        float s = 0.0f;
#pragma unroll
        for (int d4 = 0; d4 < HD_; d4 += 4) {
            float4 kk4 = *(const float4*)(kr + d4);
            s += qv[d4] * kk4.x + qv[d4 + 1] * kk4.y + qv[d4 + 2] * kk4.z + qv[d4 + 3] * kk4.w;
        }
        s *= 0.125f;
        sc[j] = s;
        lmax = fmaxf(lmax, s);
    }
    red[tid] = lmax;
    __syncthreads();
    for (int st = 128; st > 0; st >>= 1) {
        if (tid < st) red[tid] = fmaxf(red[tid], red[tid + st]);
        __syncthreads();
    }
    float m = red[0];
    __syncthreads();
    float lsum = 0.0f;
    for (int j = tid; j <= qi; j += 256) {
        float e = expf(sc[j] - m);
        sc[j] = e;
        lsum += e;
    }
    red[tid] = lsum;
    __syncthreads();
    for (int st = 128; st > 0; st >>= 1) {
        if (tid < st) red[tid] += red[tid + st];
        __syncthreads();
    }
    float inv = 1.0f / red[0];
    __syncthreads();
    int d = tid & 63, seg = tid >> 6;
    float o = 0.0f;
    for (int j = seg; j <= qi; j += 4) {
        o += sc[j] * v[((size_t)(b * S_ + j)) * D_ + h * HD_ + d];
    }
    part[seg][d] = o;
    __syncthreads();
    if (tid < HD_) {
        float r = (part[0][tid] + part[1][tid] + part[2][tid] + part[3][tid]) * inv;
        split_store(r, ctx + rowQ + tid, ctxPl);
    }
}

__global__ void zero_meta_k(int* __restrict__ counts) {
    int i = threadIdx.x;
    if (i < E_) counts[i] = 0;
}

__global__ __launch_bounds__(256) void top2_k(const float* __restrict__ logits,
                                              int* __restrict__ counts, int* __restrict__ tokE,
                                              float* __restrict__ tokW) {
    int t = blockIdx.x * 256 + threadIdx.x;
    if (t >= T_) return;
    const float* l = logits + t * E_;
    int i0 = 0;
    float v0 = l[0];
    for (int e = 1; e < E_; ++e) {
        float v = l[e];
        if (v > v0) { v0 = v; i0 = e; }
    }
    int i1 = -1;
    float v1 = -1e30f;
    for (int e = 0; e < E_; ++e) {
        if (e == i0) continue;
        float v = l[e];
        if (v > v1) { v1 = v; i1 = e; }
    }
    float e2 = expf(v1 - v0);
    float w0 = 1.0f / (1.0f + e2);
    float w1 = e2 * w0;
    tokE[2 * t] = i0;
    tokE[2 * t + 1] = i1;
    tokW[2 * t] = w0;
    tokW[2 * t + 1] = w1;
    atomicAdd(&counts[i0], 1);
    atomicAdd(&counts[i1], 1);
}

__global__ void offsets_k(const int* __restrict__ counts, int* __restrict__ offsets,
                          int* __restrict__ cursor) {
    if (threadIdx.x == 0 && blockIdx.x == 0) {
        int a = 0;
        for (int e = 0; e < E_; ++e) {
            offsets[e] = a;
            cursor[e] = a;
            a += counts[e];
        }
    }
}

__global__ __launch_bounds__(256) void assign_k(const int* __restrict__ tokE,
                                                int* __restrict__ cursor,
                                                int* __restrict__ rowTok,
                                                int* __restrict__ tokRow) {
    int t = blockIdx.x * 256 + threadIdx.x;
    if (t >= T_) return;
    for (int s = 0; s < 2; ++s) {
        int e = tokE[2 * t + s];
        int r = atomicAdd(&cursor[e], 1);
        rowTok[r] = t;
        tokRow[2 * t + s] = r;
    }
}

// gather pair rows: Ag[p][r][:] = h[p][rowTok[r]][:]
__global__ __launch_bounds__(256) void gather2_k(const short* __restrict__ h,
                                                 const int* __restrict__ rowTok,
                                                 short* __restrict__ Ag, size_t hPl, size_t aPl) {
    int id = blockIdx.x * 256 + threadIdx.x;  // r*96 + c (uint4 units)
    if (id >= 2 * T_ * 96) return;
    int p = blockIdx.y;
    int r = id / 96, c = id % 96;
    const uint4* src = (const uint4*)(h + p * hPl) + (size_t)rowTok[r] * 96 + c;
    ((uint4*)(Ag + p * aPl))[(size_t)r * 96 + c] = *src;
}

__global__ __launch_bounds__(256) void combine_k(const float* __restrict__ y2,
                                                 const int* __restrict__ tokRow,
                                                 const float* __restrict__ tokW,
                                                 float* __restrict__ x, short* __restrict__ xb,
                                                 size_t xbPl) {
    int id = blockIdx.x * 256 + threadIdx.x;
    if (id >= T_ * D_) return;
    int t = id / D_;
    float v = x[id] + tokW[2 * t] * y2[(size_t)tokRow[2 * t] * D_ + id % D_] +
              tokW[2 * t + 1] * y2[(size_t)tokRow[2 * t + 1] * D_ + id % D_];
    x[id] = v;
    split_store(v, xb + id, xbPl);
}

__global__ void pad_outb_k(const float* __restrict__ outb, float* __restrict__ obp) {
    int i = blockIdx.x * 256 + threadIdx.x;
    if (i < NPADO) obp[i] = (i < NS2) ? outb[i] : 0.0f;
}

// basisT pair [n][j], stride KPAD; j>=NS2 -> 0
__global__ __launch_bounds__(256) void basisT2_k(short* __restrict__ bT, size_t planeOff) {
    int id = blockIdx.x * 256 + threadIdx.x;
    if (id >= WIN_ * KPAD) return;
    int n = id / KPAD, j = id % KPAD;
    float val = 0.0f;
    if (j < NS2) {
        float wn = 0.5f - 0.5f * cosf(6.283185307179586f * (float)n / 1024.0f);
        int kf = (j < FBINS) ? j : (j - FBINS);
        float scale = (kf == 0 || kf == 512) ? (1.0f / 1024.0f) : (2.0f / 1024.0f);
        int m = (kf * n) & 1023;
        float th = 6.283185307179586f * (float)m / 1024.0f;
        if (j < FBINS) val = scale * cosf(th);
        else val = (kf == 0 || kf == 512) ? 0.0f : (-scale * sinf(th));
        val *= wn;
    }
    split_store(val, bT + id, planeOff);
}

__global__ __launch_bounds__(256) void ola_k(const float* __restrict__ frames,
                                             float* __restrict__ out, int total) {
    int id = blockIdx.x * 256 + threadIdx.x;
    if (id >= total) return;
    int b = id / OUTP, pout = id % OUTP;
    int p = pout + PAD_;
    int t1 = p >> 8;
    if (t1 > S_ - 1) t1 = S_ - 1;
    int t0 = p - (WIN_ - 1) + (HOP_ - 1);
    t0 = (t0 > 0) ? (t0 >> 8) : 0;
    float acc = 0.0f, env = 0.0f;
    for (int t = t0; t <= t1; ++t) {
        int n = p - (t << 8);
        float wn = 0.5f - 0.5f * cosf(6.283185307179586f * (float)n / 1024.0f);
        acc += frames[(((size_t)(b * S_ + t)) << 10) + n];
        env += wn * wn;
    }
    out[id] = acc / env;
}

// ======================= launcher =======================
extern "C" void kernel_launch(void* const* d_in, const int* in_sizes, int n_in, void* d_out,
                              int out_size, void* d_ws, size_t ws_size, hipStream_t stream) {
    const float* z    = (const float*)d_in[0];
    const float* in_w = (const float*)d_in[1];
    const float* in_b = (const float*)d_in[2];
    const float* ln1g = (const float*)d_in[3];
    const float* ln1b = (const float*)d_in[4];
    const float* wq   = (const float*)d_in[5];
    const float* bq   = (const float*)d_in[6];
    const float* wk   = (const float*)d_in[7];
    const float* bk   = (const float*)d_in[8];
    const float* wv   = (const float*)d_in[9];
    const float* bv   = (const float*)d_in[10];
    const float* wo   = (const float*)d_in[11];
    const float* bo   = (const float*)d_in[12];
    const float* ln2g = (const float*)d_in[13];
    const float* ln2b = (const float*)d_in[14];
    const float* gw   = (const float*)d_in[15];
    const float* ew1  = (const float*)d_in[16];
    const float* eb1  = (const float*)d_in[17];
    const float* ew2  = (const float*)d_in[18];
    const float* eb2  = (const float*)d_in[19];
    const float* outw = (const float*)d_in[20];
    const float* outb = (const float*)d_in[21];

    float* ws = (float*)d_ws;
    int* wsi = (int*)d_ws;
    const size_t TD = (size_t)T_ * D_;              // 1,572,864
    // ---- offsets in floats ----
    const size_t o_x      = 0;
    const size_t o_logits = TD;
    const size_t o_counts = o_logits + (size_t)T_ * E_;
    const size_t o_cursor = o_counts + 16;
    const size_t o_offs   = o_cursor + 16;
    const size_t o_tokE   = o_offs + 16;
    const size_t o_rowTok = o_tokE + 2 * T_;
    const size_t o_tokRow = o_rowTok + 2 * T_;
    const size_t o_tokW   = o_tokRow + 2 * T_;
    const size_t o_obp    = o_tokW + 2 * T_;
    const size_t o_W      = ((o_obp + NPADO + 127) / 128) * 128;
    const size_t WSLOT    = (size_t)D_ * D_;        // floats per pair slot (2*D*D shorts)
    const size_t o_q      = o_W + 4 * WSLOT;
    const size_t o_k      = o_q + TD;
    const size_t o_v      = o_k + TD;
    const size_t o_h      = o_v + TD;               // pair (2*TD shorts = TD floats)
    const size_t o_ctx    = o_h + TD;               // pair
    const size_t o_eT     = o_ctx + TD;             // 2-expert pair group = 2*FF*D floats
    const size_t o_Ag     = o_eT + 2 * (size_t)FF_ * D_;
    const size_t total_f  = o_Ag + (size_t)AGR * D_ * 2 / 2 * 2;  // pair = AGR*D floats... explicit below
    const size_t AgF      = (size_t)AGR * D_;       // floats for pair (2*AGR*D shorts)
    const size_t total    = o_Ag + AgF;
    if (ws_size < total * sizeof(float)) return;
    // overlays
    const size_t o_h1     = o_W;                    // pair [AGR][FF]: 2*AGR*FF shorts = AGR*FF floats
    const size_t o_y2     = o_Ag;                   // fp32 [2T][D]
    const size_t o_zT     = o_eT;                   // pair [T][CIN]
    const size_t o_s      = o_eT;                   // pair [T][KPAD]
    const size_t o_basisT = o_s + (size_t)T_ * KPAD;        // pair [WIN][KPAD]
    const size_t o_frames = o_basisT + (size_t)WIN_ * KPAD; // fp32 [T][WIN]
    // plane offsets (shorts)
    const size_t PL_TD   = TD;                      // h / ctx / xb planes
    const size_t PL_W    = (size_t)D_ * D_;
    const size_t PL_INW  = (size_t)D_ * CIN;
    const size_t PL_OUTW = (size_t)NPADO * D_;
    const size_t PL_E    = (size_t)FF_ * D_;
    const size_t EST     = 2 * PL_E;                // per-expert stride in group buffer
    const size_t PL_AG   = (size_t)AGR * D_;
    const size_t PL_H1   = (size_t)AGR * FF_;
    const size_t PL_ZT   = (size_t)T_ * CIN;
    const size_t PL_S    = (size_t)T_ * KPAD;
    const size_t PL_BAS  = (size_t)WIN_ * KPAD;
    const size_t WSLOTSH = 2 * PL_W;                // shorts per W slot

    dim3 blk(256);
    short* Wsh = (short*)(ws + o_W);
    short* hP  = (short*)(ws + o_h);
    short* ctxP = (short*)(ws + o_ctx);
    short* eTP = (short*)(ws + o_eT);
    short* AgP = (short*)(ws + o_Ag);
    short* h1P = (short*)(ws + o_h1);

    // ---- in projection ----
    tz2_k<<<cdiv(T_ * CIN, 256), blk, 0, stream>>>(z, (short*)(ws + o_zT), PL_ZT);
    transp2_k<<<dim3(24, 16, 1), blk, 0, stream>>>(in_w, Wsh, CIN, D_, D_, 0, 0, PL_INW);
    mm2_k<0><<<dim3(6, 16), blk, 0, stream>>>((short*)(ws + o_zT), (short*)(ws + o_zT) + PL_ZT,
                                              Wsh, Wsh + PL_INW, in_b, ws + o_x, nullptr, 0,
                                              D_, CIN, CIN, CIN, D_);

    for (int i = 0; i < 2; ++i) {
        const size_t wOff = (size_t)i * D_ * D_;
        const size_t bOff = (size_t)i * D_;
        transp2_k<<<dim3(24, 24, 1), blk, 0, stream>>>(wq + wOff, Wsh, D_, D_, D_, 0, 0, PL_W);
        transp2_k<<<dim3(24, 24, 1), blk, 0, stream>>>(wk + wOff, Wsh + WSLOTSH, D_, D_, D_, 0, 0, PL_W);
        transp2_k<<<dim3(24, 24, 1), blk, 0, stream>>>(wv + wOff, Wsh + 2 * WSLOTSH, D_, D_, D_, 0, 0, PL_W);
        transp2_k<<<dim3(24, 24, 1), blk, 0, stream>>>(wo + wOff, Wsh + 3 * WSLOTSH, D_, D_, D_, 0, 0, PL_W);

        ln_k<<<T_, blk, 0, stream>>>(ws + o_x, ln1g + bOff, ln1b + bOff, hP, PL_TD);
        mm2_k<0><<<dim3(6, 16), blk, 0, stream>>>(hP, hP + PL_TD, Wsh, Wsh + PL_W, bq + bOff,
                                                  ws + o_q, nullptr, 0, D_, D_, D_, D_, D_);
        mm2_k<0><<<dim3(6, 16), blk, 0, stream>>>(hP, hP + PL_TD, Wsh + WSLOTSH,
                                                  Wsh + WSLOTSH + PL_W, bk + bOff, ws + o_k,
                                                  nullptr, 0, D_, D_, D_, D_, D_);
        mm2_k<0><<<dim3(6, 16), blk, 0, stream>>>(hP, hP + PL_TD, Wsh + 2 * WSLOTSH,
                                                  Wsh + 2 * WSLOTSH + PL_W, bv + bOff, ws + o_v,
                                                  nullptr, 0, D_, D_, D_, D_, D_);
        if (i == 0) {
            rope_k<<<cdiv(T_ * 384, 256), blk, 0, stream>>>(ws + o_q);
            rope_k<<<cdiv(T_ * 384, 256), blk, 0, stream>>>(ws + o_k);
        }
        attn_k<<<dim3(S_, NH, B_), blk, 0, stream>>>(ws + o_q, ws + o_k, ws + o_v, ctxP, PL_TD);
        mm2_k<1><<<dim3(6, 16), blk, 0, stream>>>(ctxP, ctxP + PL_TD, Wsh + 3 * WSLOTSH,
                                                  Wsh + 3 * WSLOTSH + PL_W, bo + bOff, ws + o_x,
                                                  nullptr, 0, D_, D_, D_, D_, D_);
        // LN2 pair for FFN input + fused fp32 LN+gate for routing
        ln_k<<<T_, blk, 0, stream>>>(ws + o_x, ln2g + bOff, ln2b + bOff, hP, PL_TD);
        lngate_k<<<T_, blk, 0, stream>>>(ws + o_x, ln2g + bOff, ln2b + bOff,
                                         gw + (size_t)i * D_ * E_, ws + o_logits);
        zero_meta_k<<<1, 64, 0, stream>>>(wsi + o_counts);
        top2_k<<<cdiv(T_, 256), blk, 0, stream>>>(ws + o_logits, wsi + o_counts, wsi + o_tokE,
                                                  ws + o_tokW);
        offsets_k<<<1, 64, 0, stream>>>(wsi + o_counts, wsi + o_offs, wsi + o_cursor);
        assign_k<<<cdiv(T_, 256), blk, 0, stream>>>(wsi + o_tokE, wsi + o_cursor, wsi + o_rowTok,
                                                    wsi + o_tokRow);
        gather2_k<<<dim3(cdiv(2 * T_ * 96, 256), 2), blk, 0, stream>>>(hP, wsi + o_rowTok, AgP,
                                                                       PL_TD, PL_AG);
        // expert FFN in 4 groups of 2 experts
        for (int g = 0; g < 4; ++g) {
            transp2_k<<<dim3(64, 24, 2), blk, 0, stream>>>(
                ew1 + ((size_t)i * E_ + 2 * g) * D_ * FF_, eTP, D_, FF_, FF_,
                (size_t)D_ * FF_, EST, PL_E);
            mm2_moe_k<3><<<dim3(16, 33, 2), blk, 0, stream>>>(
                AgP, AgP + PL_AG, eTP, EST, PL_E, eb1 + (size_t)i * E_ * FF_ + 2 * g * FF_, FF_,
                nullptr, h1P, PL_H1, wsi + o_counts + 2 * g, wsi + o_offs + 2 * g,
                FF_, D_, D_, D_, FF_);
        }
        for (int g = 0; g < 4; ++g) {
            transp2_k<<<dim3(24, 64, 2), blk, 0, stream>>>(
                ew2 + ((size_t)i * E_ + 2 * g) * FF_ * D_, eTP, FF_, D_, D_,
                (size_t)FF_ * D_, EST, PL_E);
            mm2_moe_k<0><<<dim3(6, 33, 2), blk, 0, stream>>>(
                h1P, h1P + PL_H1, eTP, EST, PL_E, eb2 + (size_t)i * E_ * D_ + 2 * g * D_, D_,
                ws + o_y2, nullptr, 0, wsi + o_counts + 2 * g, wsi + o_offs + 2 * g,
                D_, FF_, FF_, FF_, D_);
        }
        combine_k<<<cdiv(T_ * D_, 256), blk, 0, stream>>>(ws + o_y2, wsi + o_tokRow, ws + o_tokW,
                                                          ws + o_x, ctxP, PL_TD);
    }

    // ---- output projection -> s pair ----
    transp2_k<<<dim3(36, 24, 1), blk, 0, stream>>>(outw, Wsh, D_, NS2, NPADO, 0, 0, PL_OUTW);
    pad_outb_k<<<cdiv(NPADO, 256), blk, 0, stream>>>(outb, ws + o_obp);
    mm2_k<2><<<dim3(NPADO / 128, 16), blk, 0, stream>>>(ctxP, ctxP + PL_TD, Wsh, Wsh + PL_OUTW,
                                                        ws + o_obp, nullptr, (short*)(ws + o_s),
                                                        PL_S, KPAD, D_, D_, D_, KPAD);
    // ---- ISTFT ----
    basisT2_k<<<cdiv(WIN_ * KPAD, 256), blk, 0, stream>>>((short*)(ws + o_basisT), PL_BAS);
    mm2_k<0><<<dim3(8, 16), blk, 0, stream>>>((short*)(ws + o_s), (short*)(ws + o_s) + PL_S,
                                              (short*)(ws + o_basisT),
                                              (short*)(ws + o_basisT) + PL_BAS, nullptr,
                                              ws + o_frames, nullptr, 0, WIN_, KPAD, KPAD, KPAD,
                                              WIN_);
    ola_k<<<cdiv(out_size, 256), blk, 0, stream>>>(ws + o_frames, (float*)d_out, out_size);
}

// Round 6
// 2551.284 us; speedup vs baseline: 1.9904x; 1.4400x over previous
//
#include <hip/hip_runtime.h>
#include <hip/hip_bf16.h>
#include <math.h>

#define B_    2
#define CIN   512
#define S_    1024
#define D_    768
#define NH    12
#define HD_   64
#define E_    8
#define FF_   2048
#define T_    2048
#define FBINS 513
#define NS2   1026
#define KPAD  1056              // NS2 padded to mult of 32
#define NPADO 1152              // NS2 padded to mult of 128
#define WIN_  1024
#define HOP_  256
#define PAD_  384
#define OUTP  262144
#define AGR   4224              // 2T + 128 pad rows

static inline int cdiv(int a, int b) { return (a + b - 1) / b; }

typedef _Float16 half8 __attribute__((ext_vector_type(8)));
typedef __attribute__((ext_vector_type(4))) float floatx4;

#define MFMA16(a, b, c) __builtin_amdgcn_mfma_f32_16x16x32_f16(a, b, c, 0, 0, 0)
#define LO_SCALE 2048.0f
#define LO_INV   (1.0f / 2048.0f)

// split fp32 -> (hi fp16, lo fp16 scaled by 2048); planes are short-typed
__device__ inline void split_store(float v, short* p, size_t planeOff) {
    _Float16 h = (_Float16)v;
    _Float16 l = (_Float16)((v - (float)h) * LO_SCALE);
    *(_Float16*)p = h;
    *(_Float16*)(p + planeOff) = l;
}

__device__ inline float gelu_f(float x) {
    float x3 = x * x * x;
    return 0.5f * x * (1.0f + tanhf(0.7978845608028654f * (x + 0.044715f * x3)));
}

__device__ inline void gl_lds16(const short* g, short* l) {
    __builtin_amdgcn_global_load_lds((const __attribute__((address_space(1))) void*)g,
                                     (__attribute__((address_space(3))) void*)l, 16, 0, 0);
}

// ===== split-fp16 MFMA GEMM core (128x128 tile, BK=32, 3 MFMAs per frag pair) =====
// MODE 0: f32 store; 1: f32 +=; 2: split-pair store; 3: gelu -> split-pair store
template <int MODE>
__global__ __launch_bounds__(256) void mm2_k(
    const short* __restrict__ Ah, const short* __restrict__ Al,
    const short* __restrict__ Bh, const short* __restrict__ Bl,
    const float* __restrict__ bias, float* __restrict__ Cf,
    short* __restrict__ Cp, size_t CpPl,
    int Nstore, int K, int SA, int SB, int SC) {
    __shared__ short AsH[4096], AsL[4096], BsH[4096], BsL[4096];
    int tid = threadIdx.x;
    int wave = tid >> 6, lane = tid & 63;
    int m0 = blockIdx.y * 128, n0 = blockIdx.x * 128;
    int wm = (wave & 1) * 64, wn = (wave >> 1) * 64;
    floatx4 a1[4][4], a2[4][4];
#pragma unroll
    for (int i = 0; i < 4; ++i)
#pragma unroll
        for (int j = 0; j < 4; ++j) {
            a1[i][j] = (floatx4){0.f, 0.f, 0.f, 0.f};
            a2[i][j] = (floatx4){0.f, 0.f, 0.f, 0.f};
        }
    int lm = lane & 15, lk = (lane >> 4) * 8;
    int fl0 = wave * 64 + lane, fl1 = fl0 + 256;
    int r0 = fl0 >> 2, c0 = (fl0 & 3) * 8;
    int r1 = fl1 >> 2, c1 = (fl1 & 3) * 8;
    int kIters = K >> 5;
    for (int kt = 0; kt < kIters; ++kt) {
        int k0 = kt << 5;
        size_t a0 = (size_t)(m0 + r0) * SA + k0 + c0;
        size_t a1o = (size_t)(m0 + r1) * SA + k0 + c1;
        size_t b0 = (size_t)(n0 + r0) * SB + k0 + c0;
        size_t b1 = (size_t)(n0 + r1) * SB + k0 + c1;
        gl_lds16(Ah + a0, AsH + wave * 512);
        gl_lds16(Ah + a1o, AsH + (wave + 4) * 512);
        gl_lds16(Al + a0, AsL + wave * 512);
        gl_lds16(Al + a1o, AsL + (wave + 4) * 512);
        gl_lds16(Bh + b0, BsH + wave * 512);
        gl_lds16(Bh + b1, BsH + (wave + 4) * 512);
        gl_lds16(Bl + b0, BsL + wave * 512);
        gl_lds16(Bl + b1, BsL + (wave + 4) * 512);
        __syncthreads();
        half8 ah[4], al[4], bh[4], bl[4];
#pragma unroll
        for (int i = 0; i < 4; ++i) {
            int off = (wm + i * 16 + lm) * 32 + lk;
            ah[i] = *(const half8*)(AsH + off);
            al[i] = *(const half8*)(AsL + off);
        }
#pragma unroll
        for (int j = 0; j < 4; ++j) {
            int off = (wn + j * 16 + lm) * 32 + lk;
            bh[j] = *(const half8*)(BsH + off);
            bl[j] = *(const half8*)(BsL + off);
        }
#pragma unroll
        for (int i = 0; i < 4; ++i)
#pragma unroll
            for (int j = 0; j < 4; ++j) {
                a1[i][j] = MFMA16(ah[i], bh[j], a1[i][j]);
                a2[i][j] = MFMA16(ah[i], bl[j], a2[i][j]);
                a2[i][j] = MFMA16(al[i], bh[j], a2[i][j]);
            }
        __syncthreads();
    }
    int row4 = (lane >> 4) * 4;
#pragma unroll
    for (int i = 0; i < 4; ++i) {
        int row = m0 + wm + i * 16 + row4;
#pragma unroll
        for (int j = 0; j < 4; ++j) {
            int col = n0 + wn + j * 16 + lm;
            if (col < Nstore) {
                float bv = bias ? bias[col] : 0.0f;
#pragma unroll
                for (int r = 0; r < 4; ++r) {
                    float v = a1[i][j][r] + a2[i][j][r] * LO_INV + bv;
                    size_t idx = (size_t)(row + r) * SC + col;
                    if (MODE == 0) Cf[idx] = v;
                    else if (MODE == 1) Cf[idx] += v;
                    else if (MODE == 2) split_store(v, Cp + idx, CpPl);
                    else split_store(gelu_f(v), Cp + idx, CpPl);
                }
            }
        }
    }
}

// ===== grouped MoE variant over expert row-segments (2 experts per launch) =====
template <int MODE>
__global__ __launch_bounds__(256) void mm2_moe_k(
    const short* __restrict__ Agh, const short* __restrict__ Agl,
    const short* __restrict__ BT, size_t eStride, size_t bPl,
    const float* __restrict__ biasAll, int biasStride,
    float* __restrict__ Cf, short* __restrict__ Cp, size_t CpPl,
    const int* __restrict__ counts, const int* __restrict__ offsets,
    int N, int K, int SA, int SB, int SC) {
    int el = blockIdx.z;
    int nrows = counts[el];
    int m0 = blockIdx.y * 128;
    if (m0 >= nrows) return;
    int base = offsets[el];
    const short* Ah = Agh + (size_t)base * SA;
    const short* Al = Agl + (size_t)base * SA;
    const short* Bh = BT + (size_t)el * eStride;
    const short* Bl = Bh + bPl;
    const float* bias = biasAll + (size_t)el * biasStride;
    __shared__ short AsH[4096], AsL[4096], BsH[4096], BsL[4096];
    int tid = threadIdx.x;
    int wave = tid >> 6, lane = tid & 63;
    int n0 = blockIdx.x * 128;
    int wm = (wave & 1) * 64, wn = (wave >> 1) * 64;
    floatx4 a1[4][4], a2[4][4];
#pragma unroll
    for (int i = 0; i < 4; ++i)
#pragma unroll
        for (int j = 0; j < 4; ++j) {
            a1[i][j] = (floatx4){0.f, 0.f, 0.f, 0.f};
            a2[i][j] = (floatx4){0.f, 0.f, 0.f, 0.f};
        }
    int lm = lane & 15, lk = (lane >> 4) * 8;
    int fl0 = wave * 64 + lane, fl1 = fl0 + 256;
    int r0 = fl0 >> 2, c0 = (fl0 & 3) * 8;
    int r1 = fl1 >> 2, c1 = (fl1 & 3) * 8;
    int kIters = K >> 5;
    for (int kt = 0; kt < kIters; ++kt) {
        int k0 = kt << 5;
        size_t a0 = (size_t)(m0 + r0) * SA + k0 + c0;
        size_t a1o = (size_t)(m0 + r1) * SA + k0 + c1;
        size_t b0 = (size_t)(n0 + r0) * SB + k0 + c0;
        size_t b1 = (size_t)(n0 + r1) * SB + k0 + c1;
        gl_lds16(Ah + a0, AsH + wave * 512);
        gl_lds16(Ah + a1o, AsH + (wave + 4) * 512);
        gl_lds16(Al + a0, AsL + wave * 512);
        gl_lds16(Al + a1o, AsL + (wave + 4) * 512);
        gl_lds16(Bh + b0, BsH + wave * 512);
        gl_lds16(Bh + b1, BsH + (wave + 4) * 512);
        gl_lds16(Bl + b0, BsL + wave * 512);
        gl_lds16(Bl + b1, BsL + (wave + 4) * 512);
        __syncthreads();
        half8 ah[4], al[4], bh[4], bl[4];
#pragma unroll
        for (int i = 0; i < 4; ++i) {
            int off = (wm + i * 16 + lm) * 32 + lk;
            ah[i] = *(const half8*)(AsH + off);
            al[i] = *(const half8*)(AsL + off);
        }
#pragma unroll
        for (int j = 0; j < 4; ++j) {
            int off = (wn + j * 16 + lm) * 32 + lk;
            bh[j] = *(const half8*)(BsH + off);
            bl[j] = *(const half8*)(BsL + off);
        }
#pragma unroll
        for (int i = 0; i < 4; ++i)
#pragma unroll
            for (int j = 0; j < 4; ++j) {
                a1[i][j] = MFMA16(ah[i], bh[j], a1[i][j]);
                a2[i][j] = MFMA16(ah[i], bl[j], a2[i][j]);
                a2[i][j] = MFMA16(al[i], bh[j], a2[i][j]);
            }
        __syncthreads();
    }
    int row4 = (lane >> 4) * 4;
#pragma unroll
    for (int i = 0; i < 4; ++i) {
        int rl = m0 + wm + i * 16 + row4;
#pragma unroll
        for (int j = 0; j < 4; ++j) {
            int col = n0 + wn + j * 16 + lm;
            if (col < N) {
                float bv = bias[col];
#pragma unroll
                for (int r = 0; r < 4; ++r) {
                    if (rl + r < nrows) {
                        float v = a1[i][j][r] + a2[i][j][r] * LO_INV + bv;
                        size_t idx = (size_t)(base + rl + r) * SC + col;
                        if (MODE == 0) Cf[idx] = v;
                        else split_store(gelu_f(v), Cp + idx, CpPl);
                    }
                }
            }
        }
    }
}

// ===== transpose fp32 [Z][R][C] -> split-pair [Z][Cout][R] (zero rows c>=C) =====
__global__ __launch_bounds__(256) void transp2_k(const float* __restrict__ src,
                                                 short* __restrict__ dst, int R, int C, int Cout,
                                                 size_t srcZ, size_t dstZ, size_t planeOff) {
    __shared__ float tile[32][33];
    int z = blockIdx.z;
    src += (size_t)z * srcZ;
    dst += (size_t)z * dstZ;
    int c0 = blockIdx.x * 32, r0 = blockIdx.y * 32;
    int tx = threadIdx.x & 31, ty = threadIdx.x >> 5;
    for (int i = ty; i < 32; i += 8) {
        int r = r0 + i, c = c0 + tx;
        tile[i][tx] = (r < R && c < C) ? src[(size_t)r * C + c] : 0.0f;
    }
    __syncthreads();
    for (int i = ty; i < 32; i += 8) {
        int cc = c0 + i, rr = r0 + tx;
        if (cc < Cout && rr < R) split_store(tile[tx][i], dst + (size_t)cc * R + rr, planeOff);
    }
}

// ===== transpose z: [B,CIN,S] -> zT pair [t][c] =====
__global__ __launch_bounds__(256) void tz2_k(const float* __restrict__ z, short* __restrict__ xT,
                                             size_t planeOff) {
    int id = blockIdx.x * 256 + threadIdx.x;
    if (id >= T_ * CIN) return;
    int t = id >> 9, c = id & 511;
    int b = t >> 10, l = t & 1023;
    split_store(z[((size_t)b * CIN + c) * S_ + l], xT + id, planeOff);
}

// ===== LayerNorm per token -> split pair =====
__global__ __launch_bounds__(256) void ln_k(const float* __restrict__ x,
                                            const float* __restrict__ g,
                                            const float* __restrict__ b, short* __restrict__ h,
                                            size_t planeOff) {
    int t = blockIdx.x;
    int tid = threadIdx.x;
    __shared__ float row[D_];
    __shared__ float red[256];
    const float* xr = x + (size_t)t * D_;
    float s = 0.0f;
    for (int i = tid; i < D_; i += 256) {
        float v = xr[i];
        row[i] = v;
        s += v;
    }
    red[tid] = s;
    __syncthreads();
    for (int st = 128; st > 0; st >>= 1) {
        if (tid < st) red[tid] += red[tid + st];
        __syncthreads();
    }
    float mean = red[0] / (float)D_;
    __syncthreads();
    float s2 = 0.0f;
    for (int i = tid; i < D_; i += 256) {
        float d = row[i] - mean;
        s2 += d * d;
    }
    red[tid] = s2;
    __syncthreads();
    for (int st = 128; st > 0; st >>= 1) {
        if (tid < st) red[tid] += red[tid + st];
        __syncthreads();
    }
    float rstd = rsqrtf(red[0] / (float)D_ + 1e-5f);
    for (int i = tid; i < D_; i += 256)
        split_store((row[i] - mean) * rstd * g[i] + b[i], h + (size_t)t * D_ + i, planeOff);
}

// ===== fused fp32 LN + gating logits =====
__global__ __launch_bounds__(256) void lngate_k(const float* __restrict__ x,
                                                const float* __restrict__ g,
                                                const float* __restrict__ b,
                                                const float* __restrict__ gw,
                                                float* __restrict__ logits) {
    int t = blockIdx.x;
    int tid = threadIdx.x;
    __shared__ float row[D_];
    __shared__ float red[256];
    const float* xr = x + (size_t)t * D_;
    float s = 0.0f;
    for (int i = tid; i < D_; i += 256) {
        float v = xr[i];
        row[i] = v;
        s += v;
    }
    red[tid] = s;
    __syncthreads();
    for (int st = 128; st > 0; st >>= 1) {
        if (tid < st) red[tid] += red[tid + st];
        __syncthreads();
    }
    float mean = red[0] / (float)D_;
    __syncthreads();
    float s2 = 0.0f;
    for (int i = tid; i < D_; i += 256) {
        float d = row[i] - mean;
        s2 += d * d;
    }
    red[tid] = s2;
    __syncthreads();
    for (int st = 128; st > 0; st >>= 1) {
        if (tid < st) red[tid] += red[tid + st];
        __syncthreads();
    }
    float rstd = rsqrtf(red[0] / (float)D_ + 1e-5f);
    __syncthreads();
    int e = tid >> 5, lane = tid & 31;
    float acc = 0.0f;
    for (int d = lane; d < D_; d += 32)
        acc += ((row[d] - mean) * rstd * g[d] + b[d]) * gw[d * E_ + e];
    red[tid] = acc;
    __syncthreads();
    for (int st = 16; st > 0; st >>= 1) {
        if (lane < st) red[tid] += red[tid + st];
        __syncthreads();
    }
    if (lane == 0) logits[t * E_ + e] = red[tid];
}

// ===== RoPE in place (fp32 q/k) =====
__global__ __launch_bounds__(256) void rope_k(float* __restrict__ x) {
    int id = blockIdx.x * 256 + threadIdx.x;
    if (id >= T_ * 384) return;
    int t = id / 384, j = id % 384;
    int pos = t & 1023;
    float inv = expf(-(float)j * (9.210340371976184f / 384.0f));
    float ang = (float)pos * inv;
    float sn, cs;
    sincosf(ang, &sn, &cs);
    float* p = x + (size_t)t * D_ + 2 * j;
    float x1 = p[0], x2 = p[1];
    p[0] = x1 * cs - x2 * sn;
    p[1] = x1 * sn + x2 * cs;
}

// ===== fp32 -> split pair, elementwise (for q, k) =====
__global__ __launch_bounds__(256) void split_k(const float* __restrict__ s,
                                               short* __restrict__ d) {
    int id = blockIdx.x * 256 + threadIdx.x;
    if (id < T_ * D_) split_store(s[id], d + id, (size_t)T_ * D_);
}

// ===== V [T][D] -> V^T pair [BH][64][S] =====
__global__ __launch_bounds__(256) void vt2_k(const float* __restrict__ v,
                                             short* __restrict__ vp) {
    __shared__ float tile[32][33];
    int bh = blockIdx.z, b = bh / NH, h = bh % NH;
    int j0 = blockIdx.x * 32, d0 = blockIdx.y * 32;
    int tx = threadIdx.x & 31, ty = threadIdx.x >> 5;
    for (int i = ty; i < 32; i += 8)
        tile[i][tx] = v[(size_t)(b * S_ + j0 + i) * D_ + h * 64 + d0 + tx];
    __syncthreads();
    for (int i = ty; i < 32; i += 8)
        split_store(tile[tx][i], vp + ((size_t)bh * 64 + d0 + i) * S_ + j0 + tx,
                    (size_t)T_ * D_);
}

// ===== flash attention: split-fp16 MFMA, online softmax, causal =====
// grid (16 q-tiles of 64 rows, 24 bh), block 256 (4 waves x 16 Q-rows)
__global__ __launch_bounds__(256) void fattn_k(const short* __restrict__ qp,
                                               const short* __restrict__ kp,
                                               const short* __restrict__ vp,
                                               short* __restrict__ ctx) {
    __shared__ short sQ[2][64 * 64];
    __shared__ short sK[2][128 * 64];
    __shared__ short sV[2][64 * 128];
    __shared__ short sP[2][4][16 * 128];
    const size_t PL = (size_t)T_ * D_;
    int qt = blockIdx.x, bh = blockIdx.y;
    int b = bh / NH, h = bh % NH;
    int tid = threadIdx.x, wave = tid >> 6, lane = tid & 63;
    int quad = lane >> 4, lm = lane & 15;
    int t0 = b * S_ + qt * 64;
    {   // stage Q: per wave, 2 chunks of 8 rows per plane
        int lr = lane >> 3, lc = (lane & 7) * 8;
#pragma unroll
        for (int pl = 0; pl < 2; ++pl)
#pragma unroll
            for (int c = 0; c < 2; ++c) {
                int r8 = wave * 16 + c * 8;
                gl_lds16(qp + pl * PL + (size_t)(t0 + r8 + lr) * D_ + h * 64 + lc,
                         &sQ[pl][r8 * 64]);
            }
    }
    floatx4 o1[4], o2[4];
#pragma unroll
    for (int n = 0; n < 4; ++n) {
        o1[n] = (floatx4){0.f, 0.f, 0.f, 0.f};
        o2[n] = (floatx4){0.f, 0.f, 0.f, 0.f};
    }
    float mrow[4] = {-1e30f, -1e30f, -1e30f, -1e30f};
    float lrow[4] = {0.f, 0.f, 0.f, 0.f};
    int ktmax = qt >> 1;
    for (int kt = 0; kt <= ktmax; ++kt) {
        {   // stage K: per wave, 4 chunks of 8 rows per plane
            int lr = lane >> 3, lc = (lane & 7) * 8;
#pragma unroll
            for (int pl = 0; pl < 2; ++pl)
#pragma unroll
                for (int c = 0; c < 4; ++c) {
                    int r8 = wave * 32 + c * 8;
                    gl_lds16(kp + pl * PL +
                                 (size_t)(b * S_ + kt * 128 + r8 + lr) * D_ + h * 64 + lc,
                             &sK[pl][r8 * 64]);
                }
            // stage V^T: per wave, 4 chunks of 4 rows (128 shorts) per plane
            int vr = lane >> 4, vc = (lane & 15) * 8;
#pragma unroll
            for (int pl = 0; pl < 2; ++pl)
#pragma unroll
                for (int c = 0; c < 4; ++c) {
                    int r4 = wave * 16 + c * 4;
                    gl_lds16(vp + pl * PL + ((size_t)bh * 64 + r4 + vr) * S_ + kt * 128 + vc,
                             &sV[pl][r4 * 128]);
                }
        }
        __syncthreads();
        // ---- S = Q K^T * scale (split-fp16) ----
        half8 qh[2], ql[2];
#pragma unroll
        for (int ks = 0; ks < 2; ++ks) {
            int off = (wave * 16 + lm) * 64 + ks * 32 + quad * 8;
            qh[ks] = *(const half8*)&sQ[0][off];
            ql[ks] = *(const half8*)&sQ[1][off];
        }
        floatx4 sacc[8];
#pragma unroll
        for (int nt = 0; nt < 8; ++nt) {
            floatx4 c1 = (floatx4){0.f, 0.f, 0.f, 0.f};
            floatx4 c2 = (floatx4){0.f, 0.f, 0.f, 0.f};
#pragma unroll
            for (int ks = 0; ks < 2; ++ks) {
                int off = (nt * 16 + lm) * 64 + ks * 32 + quad * 8;
                half8 kh = *(const half8*)&sK[0][off];
                half8 kl = *(const half8*)&sK[1][off];
                c1 = MFMA16(qh[ks], kh, c1);
                c2 = MFMA16(qh[ks], kl, c2);
                c2 = MFMA16(ql[ks], kh, c2);
            }
#pragma unroll
            for (int r = 0; r < 4; ++r) sacc[nt][r] = (c1[r] + c2[r] * LO_INV) * 0.125f;
        }
        if (kt == ktmax) {  // causal mask on the diagonal tile
#pragma unroll
            for (int nt = 0; nt < 8; ++nt) {
                int col = kt * 128 + nt * 16 + lm;
#pragma unroll
                for (int r = 0; r < 4; ++r) {
                    int rowg = qt * 64 + wave * 16 + quad * 4 + r;
                    if (col > rowg) sacc[nt][r] = -1e30f;
                }
            }
        }
        // ---- online softmax (wave-local; rows live in 16-lane quads) ----
        float mnew[4], al[4], ls[4];
#pragma unroll
        for (int r = 0; r < 4; ++r) {
            float mx = sacc[0][r];
#pragma unroll
            for (int nt = 1; nt < 8; ++nt) mx = fmaxf(mx, sacc[nt][r]);
#pragma unroll
            for (int msk = 1; msk < 16; msk <<= 1) mx = fmaxf(mx, __shfl_xor(mx, msk));
            mnew[r] = fmaxf(mrow[r], mx);
            al[r] = __expf(mrow[r] - mnew[r]);
            mrow[r] = mnew[r];
            ls[r] = 0.f;
        }
#pragma unroll
        for (int nt = 0; nt < 8; ++nt)
#pragma unroll
            for (int r = 0; r < 4; ++r) {
                float p = __expf(sacc[nt][r] - mnew[r]);
                ls[r] += p;
                _Float16 ph = (_Float16)p;
                _Float16 plo = (_Float16)((p - (float)ph) * LO_SCALE);
                int off = (quad * 4 + r) * 128 + nt * 16 + lm;
                *(_Float16*)&sP[0][wave][off] = ph;
                *(_Float16*)&sP[1][wave][off] = plo;
            }
#pragma unroll
        for (int r = 0; r < 4; ++r) {
#pragma unroll
            for (int msk = 1; msk < 16; msk <<= 1) ls[r] += __shfl_xor(ls[r], msk);
            lrow[r] = lrow[r] * al[r] + ls[r];
        }
#pragma unroll
        for (int n = 0; n < 4; ++n)
#pragma unroll
            for (int r = 0; r < 4; ++r) {
                o1[n][r] *= al[r];
                o2[n][r] *= al[r];
            }
        // ---- O += P V (split-fp16; P via per-wave LDS roundtrip) ----
        half8 ph8[4], pl8[4];
#pragma unroll
        for (int ks = 0; ks < 4; ++ks) {
            int off = lm * 128 + ks * 32 + quad * 8;
            ph8[ks] = *(const half8*)&sP[0][wave][off];
            pl8[ks] = *(const half8*)&sP[1][wave][off];
        }
#pragma unroll
        for (int nt2 = 0; nt2 < 4; ++nt2) {
#pragma unroll
            for (int ks = 0; ks < 4; ++ks) {
                int off = (nt2 * 16 + lm) * 128 + ks * 32 + quad * 8;
                half8 vh = *(const half8*)&sV[0][off];
                half8 vl = *(const half8*)&sV[1][off];
                o1[nt2] = MFMA16(ph8[ks], vh, o1[nt2]);
                o2[nt2] = MFMA16(ph8[ks], vl, o2[nt2]);
                o2[nt2] = MFMA16(pl8[ks], vh, o2[nt2]);
            }
        }
        __syncthreads();
    }
    // ---- epilogue: normalize, split-store ctx ----
#pragma unroll
    for (int r = 0; r < 4; ++r) {
        float inv = 1.0f / lrow[r];
        int rowg = t0 + wave * 16 + quad * 4 + r;
#pragma unroll
        for (int nt2 = 0; nt2 < 4; ++nt2) {
            float val = (o1[nt2][r] + o2[nt2][r] * LO_INV) * inv;
            int col = h * 64 + nt2 * 16 + lm;
            split_store(val, ctx + (size_t)rowg * D_ + col, PL);
        }
    }
}

__global__ void zero_meta_k(int* __restrict__ counts) {
    int i = threadIdx.x;
    if (i < E_) counts[i] = 0;
}

__global__ __launch_bounds__(256) void top2_k(const float* __restrict__ logits,
                                              int* __restrict__ counts, int* __restrict__ tokE,
                                              float* __restrict__ tokW) {
    int t = blockIdx.x * 256 + threadIdx.x;
    if (t >= T_) return;
    const float* l = logits + t * E_;
    int i0 = 0;
    float v0 = l[0];
    for (int e = 1; e < E_; ++e) {
        float v = l[e];
        if (v > v0) { v0 = v; i0 = e; }
    }
    int i1 = -1;
    float v1 = -1e30f;
    for (int e = 0; e < E_; ++e) {
        if (e == i0) continue;
        float v = l[e];
        if (v > v1) { v1 = v; i1 = e; }
    }
    float e2 = expf(v1 - v0);
    float w0 = 1.0f / (1.0f + e2);
    float w1 = e2 * w0;
    tokE[2 * t] = i0;
    tokE[2 * t + 1] = i1;
    tokW[2 * t] = w0;
    tokW[2 * t + 1] = w1;
    atomicAdd(&counts[i0], 1);
    atomicAdd(&counts[i1], 1);
}

__global__ void offsets_k(const int* __restrict__ counts, int* __restrict__ offsets,
                          int* __restrict__ cursor) {
    if (threadIdx.x == 0 && blockIdx.x == 0) {
        int a = 0;
        for (int e = 0; e < E_; ++e) {
            offsets[e] = a;
            cursor[e] = a;
            a += counts[e];
        }
    }
}

__global__ __launch_bounds__(256) void assign_k(const int* __restrict__ tokE,
                                                int* __restrict__ cursor,
                                                int* __restrict__ rowTok,
                                                int* __restrict__ tokRow) {
    int t = blockIdx.x * 256 + threadIdx.x;
    if (t >= T_) return;
    for (int s = 0; s < 2; ++s) {
        int e = tokE[2 * t + s];
        int r = atomicAdd(&cursor[e], 1);
        rowTok[r] = t;
        tokRow[2 * t + s] = r;
    }
}

// gather pair rows: Ag[p][r][:] = h[p][rowTok[r]][:]
__global__ __launch_bounds__(256) void gather2_k(const short* __restrict__ h,
                                                 const int* __restrict__ rowTok,
                                                 short* __restrict__ Ag, size_t hPl, size_t aPl) {
    int id = blockIdx.x * 256 + threadIdx.x;  // r*96 + c (uint4 units)
    if (id >= 2 * T_ * 96) return;
    int p = blockIdx.y;
    int r = id / 96, c = id % 96;
    const uint4* src = (const uint4*)(h + p * hPl) + (size_t)rowTok[r] * 96 + c;
    ((uint4*)(Ag + p * aPl))[(size_t)r * 96 + c] = *src;
}

__global__ __launch_bounds__(256) void combine_k(const float* __restrict__ y2,
                                                 const int* __restrict__ tokRow,
                                                 const float* __restrict__ tokW,
                                                 float* __restrict__ x, short* __restrict__ xb,
                                                 size_t xbPl) {
    int id = blockIdx.x * 256 + threadIdx.x;
    if (id >= T_ * D_) return;
    int t = id / D_;
    float v = x[id] + tokW[2 * t] * y2[(size_t)tokRow[2 * t] * D_ + id % D_] +
              tokW[2 * t + 1] * y2[(size_t)tokRow[2 * t + 1] * D_ + id % D_];
    x[id] = v;
    split_store(v, xb + id, xbPl);
}

__global__ void pad_outb_k(const float* __restrict__ outb, float* __restrict__ obp) {
    int i = blockIdx.x * 256 + threadIdx.x;
    if (i < NPADO) obp[i] = (i < NS2) ? outb[i] : 0.0f;
}

// basisT pair [n][j], stride KPAD; j>=NS2 -> 0
__global__ __launch_bounds__(256) void basisT2_k(short* __restrict__ bT, size_t planeOff) {
    int id = blockIdx.x * 256 + threadIdx.x;
    if (id >= WIN_ * KPAD) return;
    int n = id / KPAD, j = id % KPAD;
    float val = 0.0f;
    if (j < NS2) {
        float wn = 0.5f - 0.5f * cosf(6.283185307179586f * (float)n / 1024.0f);
        int kf = (j < FBINS) ? j : (j - FBINS);
        float scale = (kf == 0 || kf == 512) ? (1.0f / 1024.0f) : (2.0f / 1024.0f);
        int m = (kf * n) & 1023;
        float th = 6.283185307179586f * (float)m / 1024.0f;
        if (j < FBINS) val = scale * cosf(th);
        else val = (kf == 0 || kf == 512) ? 0.0f : (-scale * sinf(th));
        val *= wn;
    }
    split_store(val, bT + id, planeOff);
}

__global__ __launch_bounds__(256) void ola_k(const float* __restrict__ frames,
                                             float* __restrict__ out, int total) {
    int id = blockIdx.x * 256 + threadIdx.x;
    if (id >= total) return;
    int b = id / OUTP, pout = id % OUTP;
    int p = pout + PAD_;
    int t1 = p >> 8;
    if (t1 > S_ - 1) t1 = S_ - 1;
    int t0 = p - (WIN_ - 1) + (HOP_ - 1);
    t0 = (t0 > 0) ? (t0 >> 8) : 0;
    float acc = 0.0f, env = 0.0f;
    for (int t = t0; t <= t1; ++t) {
        int n = p - (t << 8);
        float wn = 0.5f - 0.5f * cosf(6.283185307179586f * (float)n / 1024.0f);
        acc += frames[(((size_t)(b * S_ + t)) << 10) + n];
        env += wn * wn;
    }
    out[id] = acc / env;
}

// ======================= launcher =======================
extern "C" void kernel_launch(void* const* d_in, const int* in_sizes, int n_in, void* d_out,
                              int out_size, void* d_ws, size_t ws_size, hipStream_t stream) {
    const float* z    = (const float*)d_in[0];
    const float* in_w = (const float*)d_in[1];
    const float* in_b = (const float*)d_in[2];
    const float* ln1g = (const float*)d_in[3];
    const float* ln1b = (const float*)d_in[4];
    const float* wq   = (const float*)d_in[5];
    const float* bq   = (const float*)d_in[6];
    const float* wk   = (const float*)d_in[7];
    const float* bk   = (const float*)d_in[8];
    const float* wv   = (const float*)d_in[9];
    const float* bv   = (const float*)d_in[10];
    const float* wo   = (const float*)d_in[11];
    const float* bo   = (const float*)d_in[12];
    const float* ln2g = (const float*)d_in[13];
    const float* ln2b = (const float*)d_in[14];
    const float* gw   = (const float*)d_in[15];
    const float* ew1  = (const float*)d_in[16];
    const float* eb1  = (const float*)d_in[17];
    const float* ew2  = (const float*)d_in[18];
    const float* eb2  = (const float*)d_in[19];
    const float* outw = (const float*)d_in[20];
    const float* outb = (const float*)d_in[21];

    float* ws = (float*)d_ws;
    int* wsi = (int*)d_ws;
    const size_t TD = (size_t)T_ * D_;
    const size_t o_x      = 0;
    const size_t o_logits = TD;
    const size_t o_counts = o_logits + (size_t)T_ * E_;
    const size_t o_cursor = o_counts + 16;
    const size_t o_offs   = o_cursor + 16;
    const size_t o_tokE   = o_offs + 16;
    const size_t o_rowTok = o_tokE + 2 * T_;
    const size_t o_tokRow = o_rowTok + 2 * T_;
    const size_t o_tokW   = o_tokRow + 2 * T_;
    const size_t o_obp    = o_tokW + 2 * T_;
    const size_t o_W      = ((o_obp + NPADO + 127) / 128) * 128;
    const size_t WSLOT    = (size_t)D_ * D_;
    const size_t o_q      = o_W + 4 * WSLOT;
    const size_t o_k      = o_q + TD;
    const size_t o_v      = o_k + TD;
    const size_t o_h      = o_v + TD;
    const size_t o_ctx    = o_h + TD;
    const size_t o_eT     = o_ctx + TD;
    const size_t o_Ag     = o_eT + 2 * (size_t)FF_ * D_;
    const size_t AgF      = (size_t)AGR * D_;
    const size_t total    = o_Ag + AgF;
    if (ws_size < total * sizeof(float)) return;
    // overlays (phase-disjoint)
    const size_t o_h1     = o_W;
    const size_t o_y2     = o_Ag;
    const size_t o_zT     = o_eT;
    const size_t o_s      = o_eT;
    const size_t o_basisT = o_s + (size_t)T_ * KPAD;
    const size_t o_frames = o_basisT + (size_t)WIN_ * KPAD;
    const size_t o_qp     = o_eT;            // attn pair buffers overlay MoE region
    const size_t o_kp     = o_eT + TD;
    const size_t o_vp     = o_eT + 2 * TD;
    // plane offsets (shorts)
    const size_t PL_TD   = TD;
    const size_t PL_W    = (size_t)D_ * D_;
    const size_t PL_INW  = (size_t)D_ * CIN;
    const size_t PL_OUTW = (size_t)NPADO * D_;
    const size_t PL_E    = (size_t)FF_ * D_;
    const size_t EST     = 2 * PL_E;
    const size_t PL_AG   = (size_t)AGR * D_;
    const size_t PL_H1   = (size_t)AGR * FF_;
    const size_t PL_ZT   = (size_t)T_ * CIN;
    const size_t PL_S    = (size_t)T_ * KPAD;
    const size_t PL_BAS  = (size_t)WIN_ * KPAD;
    const size_t WSLOTSH = 2 * PL_W;

    dim3 blk(256);
    short* Wsh  = (short*)(ws + o_W);
    short* hP   = (short*)(ws + o_h);
    short* ctxP = (short*)(ws + o_ctx);
    short* eTP  = (short*)(ws + o_eT);
    short* AgP  = (short*)(ws + o_Ag);
    short* h1P  = (short*)(ws + o_h1);
    short* qpP  = (short*)(ws + o_qp);
    short* kpP  = (short*)(ws + o_kp);
    short* vpP  = (short*)(ws + o_vp);

    // ---- in projection ----
    tz2_k<<<cdiv(T_ * CIN, 256), blk, 0, stream>>>(z, (short*)(ws + o_zT), PL_ZT);
    transp2_k<<<dim3(24, 16, 1), blk, 0, stream>>>(in_w, Wsh, CIN, D_, D_, 0, 0, PL_INW);
    mm2_k<0><<<dim3(6, 16), blk, 0, stream>>>((short*)(ws + o_zT), (short*)(ws + o_zT) + PL_ZT,
                                              Wsh, Wsh + PL_INW, in_b, ws + o_x, nullptr, 0,
                                              D_, CIN, CIN, CIN, D_);

    for (int i = 0; i < 2; ++i) {
        const size_t wOff = (size_t)i * D_ * D_;
        const size_t bOff = (size_t)i * D_;
        transp2_k<<<dim3(24, 24, 1), blk, 0, stream>>>(wq + wOff, Wsh, D_, D_, D_, 0, 0, PL_W);
        transp2_k<<<dim3(24, 24, 1), blk, 0, stream>>>(wk + wOff, Wsh + WSLOTSH, D_, D_, D_, 0, 0, PL_W);
        transp2_k<<<dim3(24, 24, 1), blk, 0, stream>>>(wv + wOff, Wsh + 2 * WSLOTSH, D_, D_, D_, 0, 0, PL_W);
        transp2_k<<<dim3(24, 24, 1), blk, 0, stream>>>(wo + wOff, Wsh + 3 * WSLOTSH, D_, D_, D_, 0, 0, PL_W);

        ln_k<<<T_, blk, 0, stream>>>(ws + o_x, ln1g + bOff, ln1b + bOff, hP, PL_TD);
        mm2_k<0><<<dim3(6, 16), blk, 0, stream>>>(hP, hP + PL_TD, Wsh, Wsh + PL_W, bq + bOff,
                                                  ws + o_q, nullptr, 0, D_, D_, D_, D_, D_);
        mm2_k<0><<<dim3(6, 16), blk, 0, stream>>>(hP, hP + PL_TD, Wsh + WSLOTSH,
                                                  Wsh + WSLOTSH + PL_W, bk + bOff, ws + o_k,
                                                  nullptr, 0, D_, D_, D_, D_, D_);
        mm2_k<0><<<dim3(6, 16), blk, 0, stream>>>(hP, hP + PL_TD, Wsh + 2 * WSLOTSH,
                                                  Wsh + 2 * WSLOTSH + PL_W, bv + bOff, ws + o_v,
                                                  nullptr, 0, D_, D_, D_, D_, D_);
        if (i == 0) {
            rope_k<<<cdiv(T_ * 384, 256), blk, 0, stream>>>(ws + o_q);
            rope_k<<<cdiv(T_ * 384, 256), blk, 0, stream>>>(ws + o_k);
        }
        // split q/k into pairs; transpose+split v per head
        split_k<<<cdiv(T_ * D_, 256), blk, 0, stream>>>(ws + o_q, qpP);
        split_k<<<cdiv(T_ * D_, 256), blk, 0, stream>>>(ws + o_k, kpP);
        vt2_k<<<dim3(32, 2, B_ * NH), blk, 0, stream>>>(ws + o_v, vpP);
        // flash attention
        fattn_k<<<dim3(16, B_ * NH), blk, 0, stream>>>(qpP, kpP, vpP, ctxP);
        mm2_k<1><<<dim3(6, 16), blk, 0, stream>>>(ctxP, ctxP + PL_TD, Wsh + 3 * WSLOTSH,
                                                  Wsh + 3 * WSLOTSH + PL_W, bo + bOff, ws + o_x,
                                                  nullptr, 0, D_, D_, D_, D_, D_);
        // LN2 pair for FFN input + fused fp32 LN+gate for routing
        ln_k<<<T_, blk, 0, stream>>>(ws + o_x, ln2g + bOff, ln2b + bOff, hP, PL_TD);
        lngate_k<<<T_, blk, 0, stream>>>(ws + o_x, ln2g + bOff, ln2b + bOff,
                                         gw + (size_t)i * D_ * E_, ws + o_logits);
        zero_meta_k<<<1, 64, 0, stream>>>(wsi + o_counts);
        top2_k<<<cdiv(T_, 256), blk, 0, stream>>>(ws + o_logits, wsi + o_counts, wsi + o_tokE,
                                                  ws + o_tokW);
        offsets_k<<<1, 64, 0, stream>>>(wsi + o_counts, wsi + o_offs, wsi + o_cursor);
        assign_k<<<cdiv(T_, 256), blk, 0, stream>>>(wsi + o_tokE, wsi + o_cursor, wsi + o_rowTok,
                                                    wsi + o_tokRow);
        gather2_k<<<dim3(cdiv(2 * T_ * 96, 256), 2), blk, 0, stream>>>(hP, wsi + o_rowTok, AgP,
                                                                       PL_TD, PL_AG);
        // expert FFN in 4 groups of 2 experts
        for (int g = 0; g < 4; ++g) {
            transp2_k<<<dim3(64, 24, 2), blk, 0, stream>>>(
                ew1 + ((size_t)i * E_ + 2 * g) * D_ * FF_, eTP, D_, FF_, FF_,
                (size_t)D_ * FF_, EST, PL_E);
            mm2_moe_k<3><<<dim3(16, 33, 2), blk, 0, stream>>>(
                AgP, AgP + PL_AG, eTP, EST, PL_E, eb1 + (size_t)i * E_ * FF_ + 2 * g * FF_, FF_,
                nullptr, h1P, PL_H1, wsi + o_counts + 2 * g, wsi + o_offs + 2 * g,
                FF_, D_, D_, D_, FF_);
        }
        for (int g = 0; g < 4; ++g) {
            transp2_k<<<dim3(24, 64, 2), blk, 0, stream>>>(
                ew2 + ((size_t)i * E_ + 2 * g) * FF_ * D_, eTP, FF_, D_, D_,
                (size_t)FF_ * D_, EST, PL_E);
            mm2_moe_k<0><<<dim3(6, 33, 2), blk, 0, stream>>>(
                h1P, h1P + PL_H1, eTP, EST, PL_E, eb2 + (size_t)i * E_ * D_ + 2 * g * D_, D_,
                ws + o_y2, nullptr, 0, wsi + o_counts + 2 * g, wsi + o_offs + 2 * g,
                D_, FF_, FF_, FF_, D_);
        }
        combine_k<<<cdiv(T_ * D_, 256), blk, 0, stream>>>(ws + o_y2, wsi + o_tokRow, ws + o_tokW,
                                                          ws + o_x, ctxP, PL_TD);
    }

    // ---- output projection -> s pair ----
    transp2_k<<<dim3(36, 24, 1), blk, 0, stream>>>(outw, Wsh, D_, NS2, NPADO, 0, 0, PL_OUTW);
    pad_outb_k<<<cdiv(NPADO, 256), blk, 0, stream>>>(outb, ws + o_obp);
    mm2_k<2><<<dim3(NPADO / 128, 16), blk, 0, stream>>>(ctxP, ctxP + PL_TD, Wsh, Wsh + PL_OUTW,
                                                        ws + o_obp, nullptr, (short*)(ws + o_s),
                                                        PL_S, KPAD, D_, D_, D_, KPAD);
    // ---- ISTFT ----
    basisT2_k<<<cdiv(WIN_ * KPAD, 256), blk, 0, stream>>>((short*)(ws + o_basisT), PL_BAS);
    mm2_k<0><<<dim3(8, 16), blk, 0, stream>>>((short*)(ws + o_s), (short*)(ws + o_s) + PL_S,
                                              (short*)(ws + o_basisT),
                                              (short*)(ws + o_basisT) + PL_BAS, nullptr,
                                              ws + o_frames, nullptr, 0, WIN_, KPAD, KPAD, KPAD,
                                              WIN_);
    ola_k<<<cdiv(out_size, 256), blk, 0, stream>>>(ws + o_frames, (float*)d_out, out_size);
}